// Round 2
// baseline (601.404 us; speedup 1.0000x reference)
//
#include <hip/hip_runtime.h>
#include <stdint.h>

typedef uint16_t u16;
typedef __attribute__((ext_vector_type(8))) short s8v;      // 8 x bf16 MFMA frag
typedef __attribute__((ext_vector_type(4))) float f32x4;
typedef __attribute__((ext_vector_type(4))) unsigned short us4;

__device__ __forceinline__ float bf2f(u16 u) {
  union { uint32_t i; float f; } x; x.i = ((uint32_t)u) << 16; return x.f;
}
__device__ __forceinline__ u16 f2bf(float f) {
  union { float f; uint32_t i; } x; x.f = f;
  uint32_t r = (x.i + 0x7FFFu + ((x.i >> 16) & 1u)) >> 16;
  return (u16)r;
}

// ---------------- GroupNorm stats: one block per (n,g), 8192 contiguous floats ----
__global__ __launch_bounds__(256) void gn_stats_kernel(const float* __restrict__ x,
                                                       float2* __restrict__ stats) {
  const int tid = threadIdx.x;
  const float* p = x + (long)blockIdx.x * 8192;
  float s = 0.f, s2 = 0.f;
#pragma unroll
  for (int it = 0; it < 8; ++it) {
    float4 v = *(const float4*)(p + it * 1024 + tid * 4);
    s  += v.x + v.y + v.z + v.w;
    s2 += v.x * v.x + v.y * v.y + v.z * v.z + v.w * v.w;
  }
#pragma unroll
  for (int off = 32; off >= 1; off >>= 1) {
    s  += __shfl_down(s, off);
    s2 += __shfl_down(s2, off);
  }
  __shared__ float ps[4], ps2[4];
  const int wv = tid >> 6, lane = tid & 63;
  if (lane == 0) { ps[wv] = s; ps2[wv] = s2; }
  __syncthreads();
  if (tid == 0) {
    float S1 = ps[0] + ps[1] + ps[2] + ps[3];
    float S2 = ps2[0] + ps2[1] + ps2[2] + ps2[3];
    float mean = S1 * (1.f / 8192.f);
    float var = S2 * (1.f / 8192.f) - mean * mean;
    stats[blockIdx.x] = make_float2(mean, rsqrtf(var + 1e-6f));
  }
}

// ---------------- fused spatial GN + q/k/v GEMM ------------------------------------
// q[n][p][o], k[n][p][o] direct; v[n][o][p] via LDS transpose epilogue
__global__ __launch_bounds__(256) void qkv_s_kernel(
    const float* __restrict__ x, const float2* __restrict__ stats,
    const float* __restrict__ gamma, const float* __restrict__ beta,
    const float* __restrict__ wq, const float* __restrict__ bq,
    const float* __restrict__ wk, const float* __restrict__ bk,
    const float* __restrict__ wv, const float* __restrict__ bv,
    u16* __restrict__ qb, u16* __restrict__ kb, u16* __restrict__ vb) {
  constexpr int LDT = 72;
  __shared__ u16 Asm[64 * LDT], Bq[64 * LDT], Bk[64 * LDT], Bv[64 * LDT];
  const int ot = blockIdx.x, pt = blockIdx.y, n = blockIdx.z;
  const int tid = threadIdx.x, wid = tid >> 6, lane = tid & 63;
  const int lhi = lane >> 4, llo = lane & 15;
  f32x4 aq[4] = {}, ak[4] = {}, av[4] = {};
  const float* xb = x + (long)n * 262144 + pt * 64;

  for (int kt = 0; kt < 4; ++kt) {
    const int c0 = kt * 64;
    __syncthreads();
    // stage A: x[c][p] tile -> Asm[p][c], GroupNorm applied
#pragma unroll
    for (int it = 0; it < 4; ++it) {
      int idx = it * 256 + tid;
      int cc = idx >> 4, pv4 = idx & 15;
      int c = c0 + cc;
      float4 v = *(const float4*)(xb + (long)c * 1024 + pv4 * 4);
      float2 st = stats[n * 32 + (c >> 3)];
      float ga = gamma[c] * st.y;
      float be = beta[c] - st.x * ga;
      Asm[(pv4 * 4 + 0) * LDT + cc] = f2bf(v.x * ga + be);
      Asm[(pv4 * 4 + 1) * LDT + cc] = f2bf(v.y * ga + be);
      Asm[(pv4 * 4 + 2) * LDT + cc] = f2bf(v.z * ga + be);
      Asm[(pv4 * 4 + 3) * LDT + cc] = f2bf(v.w * ga + be);
    }
    // stage weights W[o][c] (row-major, direct rows)
#pragma unroll
    for (int it = 0; it < 4; ++it) {
      int idx = it * 256 + tid;
      int oo = idx >> 4, cv4 = idx & 15;
      long wo = (long)(ot * 64 + oo) * 256 + c0 + cv4 * 4;
      float4 a = *(const float4*)(wq + wo);
      float4 b = *(const float4*)(wk + wo);
      float4 c4 = *(const float4*)(wv + wo);
      u16* dq = &Bq[oo * LDT + cv4 * 4];
      u16* dk = &Bk[oo * LDT + cv4 * 4];
      u16* dv = &Bv[oo * LDT + cv4 * 4];
      dq[0] = f2bf(a.x); dq[1] = f2bf(a.y); dq[2] = f2bf(a.z); dq[3] = f2bf(a.w);
      dk[0] = f2bf(b.x); dk[1] = f2bf(b.y); dk[2] = f2bf(b.z); dk[3] = f2bf(b.w);
      dv[0] = f2bf(c4.x); dv[1] = f2bf(c4.y); dv[2] = f2bf(c4.z); dv[3] = f2bf(c4.w);
    }
    __syncthreads();
#pragma unroll
    for (int kk = 0; kk < 2; ++kk) {
      const int ko = kk * 32 + lhi * 8;
      s8v a = *(const s8v*)&Asm[(wid * 16 + llo) * LDT + ko];
#pragma unroll
      for (int nf = 0; nf < 4; ++nf) {
        s8v b1 = *(const s8v*)&Bq[(nf * 16 + llo) * LDT + ko];
        aq[nf] = __builtin_amdgcn_mfma_f32_16x16x32_bf16(a, b1, aq[nf], 0, 0, 0);
        s8v b2 = *(const s8v*)&Bk[(nf * 16 + llo) * LDT + ko];
        ak[nf] = __builtin_amdgcn_mfma_f32_16x16x32_bf16(a, b2, ak[nf], 0, 0, 0);
        s8v b3 = *(const s8v*)&Bv[(nf * 16 + llo) * LDT + ko];
        av[nf] = __builtin_amdgcn_mfma_f32_16x16x32_bf16(a, b3, av[nf], 0, 0, 0);
      }
    }
  }
  // epilogue: q, k direct [p][o]
  const int p0 = pt * 64 + wid * 16, o0 = ot * 64;
  const long nbase = (long)n * 262144;
#pragma unroll
  for (int nf = 0; nf < 4; ++nf) {
    int o = o0 + nf * 16 + llo;
    float bq_ = bq[o], bk_ = bk[o];
#pragma unroll
    for (int r = 0; r < 4; ++r) {
      long off = nbase + (long)(p0 + lhi * 4 + r) * 256 + o;
      qb[off] = f2bf(aq[nf][r] + bq_);
      kb[off] = f2bf(ak[nf][r] + bk_);
    }
  }
  // v: transpose through LDS -> vb[n][o][p]
  __syncthreads();
  u16* vt_ = Asm;  // reuse as [64 p][68]
#pragma unroll
  for (int nf = 0; nf < 4; ++nf) {
    int o = nf * 16 + llo;
    float bv_ = bv[o0 + o];
#pragma unroll
    for (int r = 0; r < 4; ++r)
      vt_[(wid * 16 + lhi * 4 + r) * 68 + o] = f2bf(av[nf][r] + bv_);
  }
  __syncthreads();
#pragma unroll
  for (int it = 0; it < 4; ++it) {
    int o = it * 16 + (tid >> 4), p4 = (tid & 15) * 4;
    us4 u;
#pragma unroll
    for (int j = 0; j < 4; ++j) u[j] = vt_[(p4 + j) * 68 + o];
    *(us4*)(vb + nbase + (long)(o0 + o) * 1024 + pt * 64 + p4) = u;
  }
}

// ---------------- flash spatial attention ------------------------------------------
// grid 512 blocks (n,qtile), 4 waves; K/V fragments read direct from global (L2)
__global__ __launch_bounds__(256) void flash_kernel(const u16* __restrict__ qb,
                                                    const u16* __restrict__ kb,
                                                    const u16* __restrict__ vb,
                                                    u16* __restrict__ attb) {
  const int wg = blockIdx.x;
  const int swz = (wg & 7) * 64 + (wg >> 3);  // bijective XCD swizzle: 4 n's per XCD
  const int n = swz >> 4, qt = swz & 15;
  const int tid = threadIdx.x, wid = tid >> 6, lane = tid & 63;
  const int lhi = lane >> 4, llo = lane & 15;
  const long nbase = (long)n * 262144;

  // Q fragments for this wave's 16 rows (row = llo)
  const u16* qrow = qb + nbase + (long)(qt * 64 + wid * 16 + llo) * 256;
  s8v qa[8];
#pragma unroll
  for (int kk = 0; kk < 8; ++kk) qa[kk] = *(const s8v*)(qrow + kk * 32 + lhi * 8);

  f32x4 oacc[16] = {};
  float m_[4], l_[4];
#pragma unroll
  for (int r = 0; r < 4; ++r) { m_[r] = -3.4e38f; l_[r] = 0.f; }

  __shared__ u16 ps[64][72];  // per-wave-private 16-row P regions

  for (int jt = 0; jt < 16; ++jt) {
    const u16* kbase = kb + nbase + (long)jt * 64 * 256;
    f32x4 sacc[4] = {};
#pragma unroll
    for (int jf = 0; jf < 4; ++jf) {
      const u16* krow = kbase + (long)(jf * 16 + llo) * 256;
#pragma unroll
      for (int kk = 0; kk < 8; ++kk) {
        s8v b = *(const s8v*)(krow + kk * 32 + lhi * 8);
        sacc[jf] = __builtin_amdgcn_mfma_f32_16x16x32_bf16(qa[kk], b, sacc[jf], 0, 0, 0);
      }
    }
    // scale by c^-0.5 = 1/16
#pragma unroll
    for (int jf = 0; jf < 4; ++jf)
#pragma unroll
      for (int r = 0; r < 4; ++r) sacc[jf][r] *= 0.0625f;
    // online softmax: row r lives in lanes sharing (lhi); reduce across llo
    float sc[4];
#pragma unroll
    for (int r = 0; r < 4; ++r) {
      float mx = fmaxf(fmaxf(sacc[0][r], sacc[1][r]), fmaxf(sacc[2][r], sacc[3][r]));
      mx = fmaxf(mx, __shfl_xor(mx, 1));
      mx = fmaxf(mx, __shfl_xor(mx, 2));
      mx = fmaxf(mx, __shfl_xor(mx, 4));
      mx = fmaxf(mx, __shfl_xor(mx, 8));
      float nm = fmaxf(m_[r], mx);
      sc[r] = __expf(m_[r] - nm);
      m_[r] = nm;
    }
    float rs[4] = {0.f, 0.f, 0.f, 0.f};
#pragma unroll
    for (int jf = 0; jf < 4; ++jf)
#pragma unroll
      for (int r = 0; r < 4; ++r) {
        float p = __expf(sacc[jf][r] - m_[r]);
        rs[r] += p;
        ps[wid * 16 + lhi * 4 + r][jf * 16 + llo] = f2bf(p);
      }
#pragma unroll
    for (int r = 0; r < 4; ++r) {
      rs[r] += __shfl_xor(rs[r], 1);
      rs[r] += __shfl_xor(rs[r], 2);
      rs[r] += __shfl_xor(rs[r], 4);
      rs[r] += __shfl_xor(rs[r], 8);
      l_[r] = l_[r] * sc[r] + rs[r];
    }
    // rescale O
#pragma unroll
    for (int cf = 0; cf < 16; ++cf)
#pragma unroll
      for (int r = 0; r < 4; ++r) oacc[cf][r] *= sc[r];
    // PV: A = P (from per-wave LDS region), B = v[n][c][j] direct from global
    s8v pa[2];
#pragma unroll
    for (int kk = 0; kk < 2; ++kk)
      pa[kk] = *(const s8v*)&ps[wid * 16 + llo][kk * 32 + lhi * 8];
    const u16* vbase = vb + nbase + jt * 64;
#pragma unroll
    for (int cf = 0; cf < 16; ++cf) {
      const u16* vrow = vbase + (long)(cf * 16 + llo) * 1024;
#pragma unroll
      for (int kk = 0; kk < 2; ++kk) {
        s8v b = *(const s8v*)(vrow + kk * 32 + lhi * 8);
        oacc[cf] = __builtin_amdgcn_mfma_f32_16x16x32_bf16(pa[kk], b, oacc[cf], 0, 0, 0);
      }
    }
  }
  // epilogue: att[n][p][c]
  u16* obase = attb + nbase + (long)(qt * 64 + wid * 16) * 256;
#pragma unroll
  for (int r = 0; r < 4; ++r) {
    float inv = 1.f / l_[r];
#pragma unroll
    for (int cf = 0; cf < 16; ++cf)
      obase[(lhi * 4 + r) * 256 + cf * 16 + llo] = f2bf(oacc[cf][r] * inv);
  }
}

// ---------------- fused temporal q/k/v GEMM ----------------------------------------
// D[s][o] = sum_c x[b][c][s] * W[c][o]; all three outputs [b][s][o] bf16
__global__ __launch_bounds__(256) void qkv_t_kernel(
    const float* __restrict__ x,
    const float* __restrict__ wq, const float* __restrict__ wk, const float* __restrict__ wv,
    u16* __restrict__ qt, u16* __restrict__ kt, u16* __restrict__ vt) {
  constexpr int LDT = 72;
  __shared__ u16 Asm[64 * LDT], Bq[64 * LDT], Bk[64 * LDT], Bv[64 * LDT];
  const int ot = blockIdx.x, st = blockIdx.y, b = blockIdx.z;
  const int tid = threadIdx.x, wid = tid >> 6, lane = tid & 63;
  const int lhi = lane >> 4, llo = lane & 15;
  f32x4 aq[4] = {}, ak[4] = {}, av[4] = {};
  const int s0 = st * 64, o0 = ot * 64;
  const float* xb = x + (long)b * 4194304 + s0;

  for (int kt2 = 0; kt2 < 4; ++kt2) {
    const int c0 = kt2 * 64;
    __syncthreads();
    // stage A: x[c][s] -> Asm[s][c]
#pragma unroll
    for (int it = 0; it < 4; ++it) {
      int idx = it * 256 + tid;
      int cc = idx >> 4, sv4 = idx & 15;
      float4 v = *(const float4*)(xb + (long)(c0 + cc) * 16384 + sv4 * 4);
      Asm[(sv4 * 4 + 0) * LDT + cc] = f2bf(v.x);
      Asm[(sv4 * 4 + 1) * LDT + cc] = f2bf(v.y);
      Asm[(sv4 * 4 + 2) * LDT + cc] = f2bf(v.z);
      Asm[(sv4 * 4 + 3) * LDT + cc] = f2bf(v.w);
    }
    // stage weights W[c][o] -> B[o][c] (transpose)
#pragma unroll
    for (int it = 0; it < 4; ++it) {
      int idx = it * 256 + tid;
      int cc = idx >> 4, ov4 = idx & 15;
      long wo = (long)(c0 + cc) * 256 + o0 + ov4 * 4;
      float4 a = *(const float4*)(wq + wo);
      float4 bb = *(const float4*)(wk + wo);
      float4 c4 = *(const float4*)(wv + wo);
#pragma unroll
      for (int j = 0; j < 4; ++j) {
        Bq[(ov4 * 4 + j) * LDT + cc] = f2bf(j == 0 ? a.x : j == 1 ? a.y : j == 2 ? a.z : a.w);
        Bk[(ov4 * 4 + j) * LDT + cc] = f2bf(j == 0 ? bb.x : j == 1 ? bb.y : j == 2 ? bb.z : bb.w);
        Bv[(ov4 * 4 + j) * LDT + cc] = f2bf(j == 0 ? c4.x : j == 1 ? c4.y : j == 2 ? c4.z : c4.w);
      }
    }
    __syncthreads();
#pragma unroll
    for (int kk = 0; kk < 2; ++kk) {
      const int ko = kk * 32 + lhi * 8;
      s8v a = *(const s8v*)&Asm[(wid * 16 + llo) * LDT + ko];
#pragma unroll
      for (int nf = 0; nf < 4; ++nf) {
        s8v b1 = *(const s8v*)&Bq[(nf * 16 + llo) * LDT + ko];
        aq[nf] = __builtin_amdgcn_mfma_f32_16x16x32_bf16(a, b1, aq[nf], 0, 0, 0);
        s8v b2 = *(const s8v*)&Bk[(nf * 16 + llo) * LDT + ko];
        ak[nf] = __builtin_amdgcn_mfma_f32_16x16x32_bf16(a, b2, ak[nf], 0, 0, 0);
        s8v b3 = *(const s8v*)&Bv[(nf * 16 + llo) * LDT + ko];
        av[nf] = __builtin_amdgcn_mfma_f32_16x16x32_bf16(a, b3, av[nf], 0, 0, 0);
      }
    }
  }
  const long obase = (long)b * 4194304;
#pragma unroll
  for (int nf = 0; nf < 4; ++nf) {
    int o = o0 + nf * 16 + llo;
#pragma unroll
    for (int r = 0; r < 4; ++r) {
      long off = obase + (long)(s0 + wid * 16 + lhi * 4 + r) * 256 + o;
      qt[off] = f2bf(aq[nf][r]);
      kt[off] = f2bf(ak[nf][r]);
      vt[off] = f2bf(av[nf][r]);
    }
  }
}

// ---------------- Generic bf16-MFMA GEMM (kept for proj + final) ------------------
template <int AF32, int AKM, int BF32, int BKN, int BIAS, int RES, int OUTM>
__global__ __launch_bounds__(256) void gemm_kernel(
    const void* __restrict__ Ap, const void* __restrict__ Bp,
    const float* __restrict__ bias, const float* __restrict__ resid,
    void* __restrict__ Dp, int K, int ldA, long sA, int ldB, long sB,
    int ldD, long sD, long sRes, float alpha) {
  constexpr int LDT = 72;
  __shared__ u16 Asm[64 * LDT];
  __shared__ u16 Bsm[64 * LDT];
  const int tid = threadIdx.x;
  const int wv = tid >> 6, lane = tid & 63, lhi = lane >> 4, llo = lane & 15;
  const int m0 = blockIdx.y * 64, n0 = blockIdx.x * 64;
  const int bz = blockIdx.z;

  f32x4 acc[4] = {};

  const int nK = K >> 6;
  for (int kt = 0; kt < nK; ++kt) {
    const int k0 = kt * 64;
    __syncthreads();
#pragma unroll
    for (int it = 0; it < 4; ++it) {
      int idx = it * 256 + tid;
      if (AKM == 0) {
        int m = idx >> 4, kv = idx & 15;
        if (AF32) {
          float4 v = *(const float4*)((const float*)Ap + (long)bz * sA + (long)(m0 + m) * ldA + k0 + kv * 4);
          u16* d = &Asm[m * LDT + kv * 4];
          d[0] = f2bf(v.x); d[1] = f2bf(v.y); d[2] = f2bf(v.z); d[3] = f2bf(v.w);
        } else {
          us4 v = *(const us4*)((const u16*)Ap + (long)bz * sA + (long)(m0 + m) * ldA + k0 + kv * 4);
          *(us4*)&Asm[m * LDT + kv * 4] = v;
        }
      } else {
        int kk = idx >> 4, mv = idx & 15;
        if (AF32) {
          float4 v = *(const float4*)((const float*)Ap + (long)bz * sA + (long)(k0 + kk) * ldA + m0 + mv * 4);
          Asm[(mv * 4 + 0) * LDT + kk] = f2bf(v.x);
          Asm[(mv * 4 + 1) * LDT + kk] = f2bf(v.y);
          Asm[(mv * 4 + 2) * LDT + kk] = f2bf(v.z);
          Asm[(mv * 4 + 3) * LDT + kk] = f2bf(v.w);
        } else {
          us4 v = *(const us4*)((const u16*)Ap + (long)bz * sA + (long)(k0 + kk) * ldA + m0 + mv * 4);
#pragma unroll
          for (int j = 0; j < 4; ++j) Asm[(mv * 4 + j) * LDT + kk] = v[j];
        }
      }
    }
#pragma unroll
    for (int it = 0; it < 4; ++it) {
      int idx = it * 256 + tid;
      if (BKN == 0) {
        int nn = idx >> 4, kv = idx & 15;
        if (BF32) {
          float4 v = *(const float4*)((const float*)Bp + (long)bz * sB + (long)(n0 + nn) * ldB + k0 + kv * 4);
          u16* d = &Bsm[nn * LDT + kv * 4];
          d[0] = f2bf(v.x); d[1] = f2bf(v.y); d[2] = f2bf(v.z); d[3] = f2bf(v.w);
        } else {
          us4 v = *(const us4*)((const u16*)Bp + (long)bz * sB + (long)(n0 + nn) * ldB + k0 + kv * 4);
          *(us4*)&Bsm[nn * LDT + kv * 4] = v;
        }
      } else {
        int kk = idx >> 4, nv = idx & 15;
        if (BF32) {
          float4 v = *(const float4*)((const float*)Bp + (long)bz * sB + (long)(k0 + kk) * ldB + n0 + nv * 4);
          Bsm[(nv * 4 + 0) * LDT + kk] = f2bf(v.x);
          Bsm[(nv * 4 + 1) * LDT + kk] = f2bf(v.y);
          Bsm[(nv * 4 + 2) * LDT + kk] = f2bf(v.z);
          Bsm[(nv * 4 + 3) * LDT + kk] = f2bf(v.w);
        } else {
          us4 v = *(const us4*)((const u16*)Bp + (long)bz * sB + (long)(k0 + kk) * ldB + n0 + nv * 4);
#pragma unroll
          for (int j = 0; j < 4; ++j) Bsm[(nv * 4 + j) * LDT + kk] = v[j];
        }
      }
    }
    __syncthreads();
#pragma unroll
    for (int kk = 0; kk < 2; ++kk) {
      const int ko = kk * 32 + lhi * 8;
      s8v a = *(const s8v*)&Asm[(wv * 16 + llo) * LDT + ko];
#pragma unroll
      for (int nf = 0; nf < 4; ++nf) {
        s8v b = *(const s8v*)&Bsm[(nf * 16 + llo) * LDT + ko];
        acc[nf] = __builtin_amdgcn_mfma_f32_16x16x32_bf16(a, b, acc[nf], 0, 0, 0);
      }
    }
  }
#pragma unroll
  for (int nf = 0; nf < 4; ++nf) {
    const int col = n0 + nf * 16 + llo;
    float bn_ = (BIAS == 2) ? bias[col] : 0.f;
#pragma unroll
    for (int r = 0; r < 4; ++r) {
      const int row = m0 + wv * 16 + lhi * 4 + r;
      float val = acc[nf][r] * alpha + bn_;
      if (BIAS == 1) val += bias[row];
      long off = (long)bz * sD + (long)row * ldD + col;
      if (RES) val += resid[(long)bz * sRes + (long)row * ldD + col];
      if (OUTM == 0)      ((float*)Dp)[off] = val;
      else if (OUTM == 1) ((float*)Dp)[off] += val;
      else                ((u16*)Dp)[off] = f2bf(val);
    }
  }
}

// ---------------- temporal axial attention: block per (b,hw), 8 heads, T=16 -------
__global__ __launch_bounds__(256) void tattn_kernel(const u16* __restrict__ qt,
                                                    const u16* __restrict__ kt,
                                                    const u16* __restrict__ vt,
                                                    u16* __restrict__ ot) {
  const int bi = blockIdx.x >> 10, hw = blockIdx.x & 1023;
  const long base = (long)bi * 4194304 + (long)hw * 256;
  __shared__ float qs[16][260], ks[16][260], vs[16][260];
  __shared__ u16 os[16][256];
  const int tid = threadIdx.x;
#pragma unroll
  for (int it = 0; it < 4; ++it) {
    int idx = it * 256 + tid;
    int t = idx >> 6, cv = idx & 63;
    long g = base + (long)t * 262144 + cv * 4;
    us4 a = *(const us4*)(qt + g);
    us4 b = *(const us4*)(kt + g);
    us4 c = *(const us4*)(vt + g);
#pragma unroll
    for (int j = 0; j < 4; ++j) {
      qs[t][cv * 4 + j] = bf2f(a[j]);
      ks[t][cv * 4 + j] = bf2f(b[j]);
      vs[t][cv * 4 + j] = bf2f(c[j]);
    }
  }
  __syncthreads();
  if (tid < 128) {
    const int h = tid >> 4, t = tid & 15;
    const int c0 = h * 32;
    float sc[16];
    float mx = -3.4e38f;
#pragma unroll
    for (int t2 = 0; t2 < 16; ++t2) {
      float d = 0.f;
#pragma unroll
      for (int dd = 0; dd < 32; ++dd) d += qs[t][c0 + dd] * ks[t2][c0 + dd];
      sc[t2] = d * 0.17677669529663687f;
      mx = fmaxf(mx, sc[t2]);
    }
    float sum = 0.f;
#pragma unroll
    for (int t2 = 0; t2 < 16; ++t2) { sc[t2] = __expf(sc[t2] - mx); sum += sc[t2]; }
    float inv = 1.f / sum;
#pragma unroll
    for (int dd = 0; dd < 32; ++dd) {
      float o = 0.f;
#pragma unroll
      for (int t2 = 0; t2 < 16; ++t2) o += sc[t2] * vs[t2][c0 + dd];
      os[t][c0 + dd] = f2bf(o * inv);
    }
  }
  __syncthreads();
#pragma unroll
  for (int it = 0; it < 4; ++it) {
    int idx = it * 256 + tid;
    int t = idx >> 6, cv = idx & 63;
    us4 o4;
#pragma unroll
    for (int j = 0; j < 4; ++j) o4[j] = os[t][cv * 4 + j];
    *(us4*)(ot + base + (long)t * 262144 + cv * 4) = o4;
  }
}

// =================================================================================
extern "C" void kernel_launch(void* const* d_in, const int* in_sizes, int n_in,
                              void* d_out, int out_size, void* d_ws, size_t ws_size,
                              hipStream_t stream) {
  const float* x     = (const float*)d_in[0];
  const float* gam   = (const float*)d_in[1];
  const float* bet   = (const float*)d_in[2];
  const float* wq_s  = (const float*)d_in[3];
  const float* bq_s  = (const float*)d_in[4];
  const float* wk_s  = (const float*)d_in[5];
  const float* bk_s  = (const float*)d_in[6];
  const float* wv_s  = (const float*)d_in[7];
  const float* bv_s  = (const float*)d_in[8];
  const float* wo_s  = (const float*)d_in[9];
  const float* bo_s  = (const float*)d_in[10];
  const float* wq_t  = (const float*)d_in[11];
  const float* wk_t  = (const float*)d_in[12];
  const float* wv_t  = (const float*)d_in[13];
  const float* wf_t  = (const float*)d_in[14];
  const float* bf_t  = (const float*)d_in[15];
  float* out = (float*)d_out;

  u16* qb   = (u16*)d_ws;           // [32][1024][256]
  u16* kb   = qb + 8388608;         // [32][1024][256]
  u16* vb   = kb + 8388608;         // [32][256][1024]
  u16* attb = vb + 8388608;         // [32][1024][256]
  float2* stats = (float2*)(attb + 8388608);
  u16* qt = qb; u16* kt = kb; u16* vt = vb; u16* ot = attb;  // temporal aliases

  gn_stats_kernel<<<1024, 256, 0, stream>>>(x, stats);
  qkv_s_kernel<<<dim3(4, 16, 32), 256, 0, stream>>>(x, stats, gam, bet,
      wq_s, bq_s, wk_s, bk_s, wv_s, bv_s, qb, kb, vb);
  flash_kernel<<<512, 256, 0, stream>>>(qb, kb, vb, attb);
  // proj: out[n][o][p] = x + bo[o] + wo[o][c] . att[p][c]  (f32 out, residual)
  gemm_kernel<1,0,0,0,1,1,0><<<dim3(16,4,32),256,0,stream>>>(wo_s, attb, bo_s, x, out, 256, 256, 0L, 256, 262144L, 1024, 262144L, 262144L, 1.f);
  qkv_t_kernel<<<dim3(4, 256, 2), 256, 0, stream>>>(x, wq_t, wk_t, wv_t, qt, kt, vt);
  tattn_kernel<<<2048, 256, 0, stream>>>(qt, kt, vt, ot);
  // final: out[b][o][s] += bf[o] + wf_t[c][o] . ot[s][c]  (f32 accumulate)
  gemm_kernel<1,1,0,0,1,0,1><<<dim3(256,4,2),256,0,stream>>>(wf_t, ot, bf_t, nullptr, out, 256, 256, 0L, 256, 4194304L, 16384, 4194304L, 0L, 1.f);
}

// Round 3
// 353.441 us; speedup vs baseline: 1.7016x; 1.7016x over previous
//
#include <hip/hip_runtime.h>
#include <stdint.h>

typedef uint16_t u16;
typedef __attribute__((ext_vector_type(8))) short s8v;      // 8 x bf16 MFMA frag
typedef __attribute__((ext_vector_type(4))) float f32x4;
typedef __attribute__((ext_vector_type(4))) unsigned short us4;

__device__ __forceinline__ float bf2f(u16 u) {
  union { uint32_t i; float f; } x; x.i = ((uint32_t)u) << 16; return x.f;
}
__device__ __forceinline__ u16 f2bf(float f) {
  union { float f; uint32_t i; } x; x.f = f;
  uint32_t r = (x.i + 0x7FFFu + ((x.i >> 16) & 1u)) >> 16;
  return (u16)r;
}
__device__ __forceinline__ void gl2lds16(const u16* g, u16* l) {
  __builtin_amdgcn_global_load_lds(
      (const __attribute__((address_space(1))) uint32_t*)g,
      (__attribute__((address_space(3))) uint32_t*)l, 16, 0, 0);
}

// ---------------- GroupNorm stats: one block per (n,g), 8192 contiguous floats ----
__global__ __launch_bounds__(256) void gn_stats_kernel(const float* __restrict__ x,
                                                       float2* __restrict__ stats) {
  const int tid = threadIdx.x;
  const float* p = x + (long)blockIdx.x * 8192;
  float s = 0.f, s2 = 0.f;
#pragma unroll
  for (int it = 0; it < 8; ++it) {
    float4 v = *(const float4*)(p + it * 1024 + tid * 4);
    s  += v.x + v.y + v.z + v.w;
    s2 += v.x * v.x + v.y * v.y + v.z * v.z + v.w * v.w;
  }
#pragma unroll
  for (int off = 32; off >= 1; off >>= 1) {
    s  += __shfl_down(s, off);
    s2 += __shfl_down(s2, off);
  }
  __shared__ float ps[4], ps2[4];
  const int wv = tid >> 6, lane = tid & 63;
  if (lane == 0) { ps[wv] = s; ps2[wv] = s2; }
  __syncthreads();
  if (tid == 0) {
    float S1 = ps[0] + ps[1] + ps[2] + ps[3];
    float S2 = ps2[0] + ps2[1] + ps2[2] + ps2[3];
    float mean = S1 * (1.f / 8192.f);
    float var = S2 * (1.f / 8192.f) - mean * mean;
    stats[blockIdx.x] = make_float2(mean, rsqrtf(var + 1e-6f));
  }
}

// ---------------- fused spatial GN + q/k/v GEMM ------------------------------------
__global__ __launch_bounds__(256) void qkv_s_kernel(
    const float* __restrict__ x, const float2* __restrict__ stats,
    const float* __restrict__ gamma, const float* __restrict__ beta,
    const float* __restrict__ wq, const float* __restrict__ bq,
    const float* __restrict__ wk, const float* __restrict__ bk,
    const float* __restrict__ wv, const float* __restrict__ bv,
    u16* __restrict__ qb, u16* __restrict__ kb, u16* __restrict__ vb) {
  constexpr int LDT = 72;
  __shared__ u16 Asm[64 * LDT], Bq[64 * LDT], Bk[64 * LDT], Bv[64 * LDT];
  const int ot = blockIdx.x, pt = blockIdx.y, n = blockIdx.z;
  const int tid = threadIdx.x, wid = tid >> 6, lane = tid & 63;
  const int lhi = lane >> 4, llo = lane & 15;
  f32x4 aq[4] = {}, ak[4] = {}, av[4] = {};
  const float* xb = x + (long)n * 262144 + pt * 64;

  for (int kt = 0; kt < 4; ++kt) {
    const int c0 = kt * 64;
    __syncthreads();
#pragma unroll
    for (int it = 0; it < 4; ++it) {
      int idx = it * 256 + tid;
      int cc = idx >> 4, pv4 = idx & 15;
      int c = c0 + cc;
      float4 v = *(const float4*)(xb + (long)c * 1024 + pv4 * 4);
      float2 st = stats[n * 32 + (c >> 3)];
      float ga = gamma[c] * st.y;
      float be = beta[c] - st.x * ga;
      Asm[(pv4 * 4 + 0) * LDT + cc] = f2bf(v.x * ga + be);
      Asm[(pv4 * 4 + 1) * LDT + cc] = f2bf(v.y * ga + be);
      Asm[(pv4 * 4 + 2) * LDT + cc] = f2bf(v.z * ga + be);
      Asm[(pv4 * 4 + 3) * LDT + cc] = f2bf(v.w * ga + be);
    }
#pragma unroll
    for (int it = 0; it < 4; ++it) {
      int idx = it * 256 + tid;
      int oo = idx >> 4, cv4 = idx & 15;
      long wo = (long)(ot * 64 + oo) * 256 + c0 + cv4 * 4;
      float4 a = *(const float4*)(wq + wo);
      float4 b = *(const float4*)(wk + wo);
      float4 c4 = *(const float4*)(wv + wo);
      u16* dq = &Bq[oo * LDT + cv4 * 4];
      u16* dk = &Bk[oo * LDT + cv4 * 4];
      u16* dv = &Bv[oo * LDT + cv4 * 4];
      dq[0] = f2bf(a.x); dq[1] = f2bf(a.y); dq[2] = f2bf(a.z); dq[3] = f2bf(a.w);
      dk[0] = f2bf(b.x); dk[1] = f2bf(b.y); dk[2] = f2bf(b.z); dk[3] = f2bf(b.w);
      dv[0] = f2bf(c4.x); dv[1] = f2bf(c4.y); dv[2] = f2bf(c4.z); dv[3] = f2bf(c4.w);
    }
    __syncthreads();
#pragma unroll
    for (int kk = 0; kk < 2; ++kk) {
      const int ko = kk * 32 + lhi * 8;
      s8v a = *(const s8v*)&Asm[(wid * 16 + llo) * LDT + ko];
#pragma unroll
      for (int nf = 0; nf < 4; ++nf) {
        s8v b1 = *(const s8v*)&Bq[(nf * 16 + llo) * LDT + ko];
        aq[nf] = __builtin_amdgcn_mfma_f32_16x16x32_bf16(a, b1, aq[nf], 0, 0, 0);
        s8v b2 = *(const s8v*)&Bk[(nf * 16 + llo) * LDT + ko];
        ak[nf] = __builtin_amdgcn_mfma_f32_16x16x32_bf16(a, b2, ak[nf], 0, 0, 0);
        s8v b3 = *(const s8v*)&Bv[(nf * 16 + llo) * LDT + ko];
        av[nf] = __builtin_amdgcn_mfma_f32_16x16x32_bf16(a, b3, av[nf], 0, 0, 0);
      }
    }
  }
  const int p0 = pt * 64 + wid * 16, o0 = ot * 64;
  const long nbase = (long)n * 262144;
#pragma unroll
  for (int nf = 0; nf < 4; ++nf) {
    int o = o0 + nf * 16 + llo;
    float bq_ = bq[o], bk_ = bk[o];
#pragma unroll
    for (int r = 0; r < 4; ++r) {
      long off = nbase + (long)(p0 + lhi * 4 + r) * 256 + o;
      qb[off] = f2bf(aq[nf][r] + bq_);
      kb[off] = f2bf(ak[nf][r] + bk_);
    }
  }
  __syncthreads();
  u16* vt_ = Asm;  // reuse as [64 p][68]
#pragma unroll
  for (int nf = 0; nf < 4; ++nf) {
    int o = nf * 16 + llo;
    float bv_ = bv[o0 + o];
#pragma unroll
    for (int r = 0; r < 4; ++r)
      vt_[(wid * 16 + lhi * 4 + r) * 68 + o] = f2bf(av[nf][r] + bv_);
  }
  __syncthreads();
#pragma unroll
  for (int it = 0; it < 4; ++it) {
    int o = it * 16 + (tid >> 4), p4 = (tid & 15) * 4;
    us4 u;
#pragma unroll
    for (int j = 0; j < 4; ++j) u[j] = vt_[(p4 + j) * 68 + o];
    *(us4*)(vb + nbase + (long)(o0 + o) * 1024 + pt * 64 + p4) = u;
  }
}

// ---------------- flash spatial attention v2 ---------------------------------------
// 256 blocks (n x 8 qtiles of 128 rows), 8 waves; K/V LDS double-buffered via
// global_load_lds (linear dest, XOR-swizzled source, same XOR on ds_read).
__global__ __launch_bounds__(512, 2) void flash_kernel(const u16* __restrict__ qb,
                                                       const u16* __restrict__ kb,
                                                       const u16* __restrict__ vb,
                                                       u16* __restrict__ attb) {
  const int wg = blockIdx.x;
  const int swz = (wg & 7) * 32 + (wg >> 3);  // 4 consecutive n per XCD
  const int n = swz >> 3, qt = swz & 7;
  const int tid = threadIdx.x, wid = tid >> 6, lane = tid & 63;
  const int lhi = lane >> 4, llo = lane & 15;
  const long nbase = (long)n * 262144;

  __shared__ u16 Kb[2][64 * 256];    // [row p][256 c], rows 512B, chunk^=(row&7)
  __shared__ u16 Vb[2][256 * 64];    // [row c][64 j],  rows 128B, chunk^=(row&7)
  __shared__ u16 ps[128][72];        // per-wave-private P tiles

  // Q fragments: wave's 16 rows (row = llo)
  const u16* qrow = qb + nbase + (long)(qt * 128 + wid * 16 + llo) * 256;
  s8v qa[8];
#pragma unroll
  for (int kk = 0; kk < 8; ++kk) qa[kk] = *(const s8v*)(qrow + kk * 32 + lhi * 8);

  f32x4 oacc[16] = {};
  float m_[4], l_[4];
#pragma unroll
  for (int r = 0; r < 4; ++r) { m_[r] = -3.4e38f; l_[r] = 0.f; }

  const int l5 = lane >> 5, c16 = lane & 31, l3 = lane >> 3, ch8 = lane & 7;

  auto stageKV = [&](int jt2, int b) {
    const u16* kbase = kb + nbase + (long)jt2 * 64 * 256;
    const u16* vbase = vb + nbase + (long)jt2 * 64;
#pragma unroll
    for (int ii = 0; ii < 4; ++ii) {
      int i = wid * 4 + ii;
      int r = i * 2 + l5;
      gl2lds16(kbase + (long)r * 256 + ((c16 ^ (r & 7)) * 8), &Kb[b][i * 512]);
    }
#pragma unroll
    for (int ii = 0; ii < 4; ++ii) {
      int i = wid * 4 + ii;
      int c = i * 8 + l3;
      gl2lds16(vbase + (long)c * 1024 + ((ch8 ^ (c & 7)) * 8), &Vb[b][i * 512]);
    }
  };

  stageKV(0, 0);
  __syncthreads();

  for (int jt = 0; jt < 16; ++jt) {
    const int cur = jt & 1;
    if (jt < 15) stageKV(jt + 1, cur ^ 1);

    // ---- QK^T from LDS
    f32x4 sacc[4] = {};
#pragma unroll
    for (int jf = 0; jf < 4; ++jf) {
      const int row = jf * 16 + llo;
      const u16* kr = &Kb[cur][row * 256];
#pragma unroll
      for (int kk = 0; kk < 8; ++kk) {
        const int chunk = (kk * 4 + lhi) ^ (row & 7);
        s8v b = *(const s8v*)(kr + chunk * 8);
        sacc[jf] = __builtin_amdgcn_mfma_f32_16x16x32_bf16(qa[kk], b, sacc[jf], 0, 0, 0);
      }
    }
#pragma unroll
    for (int jf = 0; jf < 4; ++jf)
#pragma unroll
      for (int r = 0; r < 4; ++r) sacc[jf][r] *= 0.0625f;
    // ---- online softmax
    float sc[4];
#pragma unroll
    for (int r = 0; r < 4; ++r) {
      float mx = fmaxf(fmaxf(sacc[0][r], sacc[1][r]), fmaxf(sacc[2][r], sacc[3][r]));
      mx = fmaxf(mx, __shfl_xor(mx, 1));
      mx = fmaxf(mx, __shfl_xor(mx, 2));
      mx = fmaxf(mx, __shfl_xor(mx, 4));
      mx = fmaxf(mx, __shfl_xor(mx, 8));
      float nm = fmaxf(m_[r], mx);
      sc[r] = __expf(m_[r] - nm);
      m_[r] = nm;
    }
    float rs[4] = {0.f, 0.f, 0.f, 0.f};
#pragma unroll
    for (int jf = 0; jf < 4; ++jf)
#pragma unroll
      for (int r = 0; r < 4; ++r) {
        float p = __expf(sacc[jf][r] - m_[r]);
        rs[r] += p;
        ps[wid * 16 + lhi * 4 + r][jf * 16 + llo] = f2bf(p);
      }
#pragma unroll
    for (int r = 0; r < 4; ++r) {
      rs[r] += __shfl_xor(rs[r], 1);
      rs[r] += __shfl_xor(rs[r], 2);
      rs[r] += __shfl_xor(rs[r], 4);
      rs[r] += __shfl_xor(rs[r], 8);
      l_[r] = l_[r] * sc[r] + rs[r];
    }
#pragma unroll
    for (int cf = 0; cf < 16; ++cf)
#pragma unroll
      for (int r = 0; r < 4; ++r) oacc[cf][r] *= sc[r];
    // ---- PV from LDS
    s8v pa[2];
#pragma unroll
    for (int kk = 0; kk < 2; ++kk)
      pa[kk] = *(const s8v*)&ps[wid * 16 + llo][kk * 32 + lhi * 8];
#pragma unroll
    for (int cf = 0; cf < 16; ++cf) {
      const int c = cf * 16 + llo;
      const u16* vr = &Vb[cur][c * 64];
#pragma unroll
      for (int kk = 0; kk < 2; ++kk) {
        const int chunk = (kk * 4 + lhi) ^ (c & 7);
        s8v b = *(const s8v*)(vr + chunk * 8);
        oacc[cf] = __builtin_amdgcn_mfma_f32_16x16x32_bf16(pa[kk], b, oacc[cf], 0, 0, 0);
      }
    }
    __syncthreads();  // drains next-tile loads (vmcnt 0) + protects buffers
  }
  // ---- epilogue: att[n][p][c]
  u16* obase = attb + nbase + (long)(qt * 128 + wid * 16) * 256;
#pragma unroll
  for (int r = 0; r < 4; ++r) {
    float inv = 1.f / l_[r];
#pragma unroll
    for (int cf = 0; cf < 16; ++cf)
      obase[(lhi * 4 + r) * 256 + cf * 16 + llo] = f2bf(oacc[cf][r] * inv);
  }
}

// ---------------- fused temporal q/k/v GEMM ----------------------------------------
__global__ __launch_bounds__(256) void qkv_t_kernel(
    const float* __restrict__ x,
    const float* __restrict__ wq, const float* __restrict__ wk, const float* __restrict__ wv,
    u16* __restrict__ qt, u16* __restrict__ kt, u16* __restrict__ vt) {
  constexpr int LDT = 72;
  __shared__ u16 Asm[64 * LDT], Bq[64 * LDT], Bk[64 * LDT], Bv[64 * LDT];
  const int ot = blockIdx.x, st = blockIdx.y, b = blockIdx.z;
  const int tid = threadIdx.x, wid = tid >> 6, lane = tid & 63;
  const int lhi = lane >> 4, llo = lane & 15;
  f32x4 aq[4] = {}, ak[4] = {}, av[4] = {};
  const int s0 = st * 64, o0 = ot * 64;
  const float* xb = x + (long)b * 4194304 + s0;

  for (int kt2 = 0; kt2 < 4; ++kt2) {
    const int c0 = kt2 * 64;
    __syncthreads();
#pragma unroll
    for (int it = 0; it < 4; ++it) {
      int idx = it * 256 + tid;
      int cc = idx >> 4, sv4 = idx & 15;
      float4 v = *(const float4*)(xb + (long)(c0 + cc) * 16384 + sv4 * 4);
      Asm[(sv4 * 4 + 0) * LDT + cc] = f2bf(v.x);
      Asm[(sv4 * 4 + 1) * LDT + cc] = f2bf(v.y);
      Asm[(sv4 * 4 + 2) * LDT + cc] = f2bf(v.z);
      Asm[(sv4 * 4 + 3) * LDT + cc] = f2bf(v.w);
    }
#pragma unroll
    for (int it = 0; it < 4; ++it) {
      int idx = it * 256 + tid;
      int cc = idx >> 4, ov4 = idx & 15;
      long wo = (long)(c0 + cc) * 256 + o0 + ov4 * 4;
      float4 a = *(const float4*)(wq + wo);
      float4 bb = *(const float4*)(wk + wo);
      float4 c4 = *(const float4*)(wv + wo);
#pragma unroll
      for (int j = 0; j < 4; ++j) {
        Bq[(ov4 * 4 + j) * LDT + cc] = f2bf(j == 0 ? a.x : j == 1 ? a.y : j == 2 ? a.z : a.w);
        Bk[(ov4 * 4 + j) * LDT + cc] = f2bf(j == 0 ? bb.x : j == 1 ? bb.y : j == 2 ? bb.z : bb.w);
        Bv[(ov4 * 4 + j) * LDT + cc] = f2bf(j == 0 ? c4.x : j == 1 ? c4.y : j == 2 ? c4.z : c4.w);
      }
    }
    __syncthreads();
#pragma unroll
    for (int kk = 0; kk < 2; ++kk) {
      const int ko = kk * 32 + lhi * 8;
      s8v a = *(const s8v*)&Asm[(wid * 16 + llo) * LDT + ko];
#pragma unroll
      for (int nf = 0; nf < 4; ++nf) {
        s8v b1 = *(const s8v*)&Bq[(nf * 16 + llo) * LDT + ko];
        aq[nf] = __builtin_amdgcn_mfma_f32_16x16x32_bf16(a, b1, aq[nf], 0, 0, 0);
        s8v b2 = *(const s8v*)&Bk[(nf * 16 + llo) * LDT + ko];
        ak[nf] = __builtin_amdgcn_mfma_f32_16x16x32_bf16(a, b2, ak[nf], 0, 0, 0);
        s8v b3 = *(const s8v*)&Bv[(nf * 16 + llo) * LDT + ko];
        av[nf] = __builtin_amdgcn_mfma_f32_16x16x32_bf16(a, b3, av[nf], 0, 0, 0);
      }
    }
  }
  const long obase = (long)b * 4194304;
#pragma unroll
  for (int nf = 0; nf < 4; ++nf) {
    int o = o0 + nf * 16 + llo;
#pragma unroll
    for (int r = 0; r < 4; ++r) {
      long off = obase + (long)(s0 + wid * 16 + lhi * 4 + r) * 256 + o;
      qt[off] = f2bf(aq[nf][r]);
      kt[off] = f2bf(ak[nf][r]);
      vt[off] = f2bf(av[nf][r]);
    }
  }
}

// ---------------- Generic bf16-MFMA GEMM (kept for proj + final) ------------------
template <int AF32, int AKM, int BF32, int BKN, int BIAS, int RES, int OUTM>
__global__ __launch_bounds__(256) void gemm_kernel(
    const void* __restrict__ Ap, const void* __restrict__ Bp,
    const float* __restrict__ bias, const float* __restrict__ resid,
    void* __restrict__ Dp, int K, int ldA, long sA, int ldB, long sB,
    int ldD, long sD, long sRes, float alpha) {
  constexpr int LDT = 72;
  __shared__ u16 Asm[64 * LDT];
  __shared__ u16 Bsm[64 * LDT];
  const int tid = threadIdx.x;
  const int wv = tid >> 6, lane = tid & 63, lhi = lane >> 4, llo = lane & 15;
  const int m0 = blockIdx.y * 64, n0 = blockIdx.x * 64;
  const int bz = blockIdx.z;

  f32x4 acc[4] = {};

  const int nK = K >> 6;
  for (int kt = 0; kt < nK; ++kt) {
    const int k0 = kt * 64;
    __syncthreads();
#pragma unroll
    for (int it = 0; it < 4; ++it) {
      int idx = it * 256 + tid;
      if (AKM == 0) {
        int m = idx >> 4, kv = idx & 15;
        if (AF32) {
          float4 v = *(const float4*)((const float*)Ap + (long)bz * sA + (long)(m0 + m) * ldA + k0 + kv * 4);
          u16* d = &Asm[m * LDT + kv * 4];
          d[0] = f2bf(v.x); d[1] = f2bf(v.y); d[2] = f2bf(v.z); d[3] = f2bf(v.w);
        } else {
          us4 v = *(const us4*)((const u16*)Ap + (long)bz * sA + (long)(m0 + m) * ldA + k0 + kv * 4);
          *(us4*)&Asm[m * LDT + kv * 4] = v;
        }
      } else {
        int kk = idx >> 4, mv = idx & 15;
        if (AF32) {
          float4 v = *(const float4*)((const float*)Ap + (long)bz * sA + (long)(k0 + kk) * ldA + m0 + mv * 4);
          Asm[(mv * 4 + 0) * LDT + kk] = f2bf(v.x);
          Asm[(mv * 4 + 1) * LDT + kk] = f2bf(v.y);
          Asm[(mv * 4 + 2) * LDT + kk] = f2bf(v.z);
          Asm[(mv * 4 + 3) * LDT + kk] = f2bf(v.w);
        } else {
          us4 v = *(const us4*)((const u16*)Ap + (long)bz * sA + (long)(k0 + kk) * ldA + m0 + mv * 4);
#pragma unroll
          for (int j = 0; j < 4; ++j) Asm[(mv * 4 + j) * LDT + kk] = v[j];
        }
      }
    }
#pragma unroll
    for (int it = 0; it < 4; ++it) {
      int idx = it * 256 + tid;
      if (BKN == 0) {
        int nn = idx >> 4, kv = idx & 15;
        if (BF32) {
          float4 v = *(const float4*)((const float*)Bp + (long)bz * sB + (long)(n0 + nn) * ldB + k0 + kv * 4);
          u16* d = &Bsm[nn * LDT + kv * 4];
          d[0] = f2bf(v.x); d[1] = f2bf(v.y); d[2] = f2bf(v.z); d[3] = f2bf(v.w);
        } else {
          us4 v = *(const us4*)((const u16*)Bp + (long)bz * sB + (long)(n0 + nn) * ldB + k0 + kv * 4);
          *(us4*)&Bsm[nn * LDT + kv * 4] = v;
        }
      } else {
        int kk = idx >> 4, nv = idx & 15;
        if (BF32) {
          float4 v = *(const float4*)((const float*)Bp + (long)bz * sB + (long)(k0 + kk) * ldB + n0 + nv * 4);
          Bsm[(nv * 4 + 0) * LDT + kk] = f2bf(v.x);
          Bsm[(nv * 4 + 1) * LDT + kk] = f2bf(v.y);
          Bsm[(nv * 4 + 2) * LDT + kk] = f2bf(v.z);
          Bsm[(nv * 4 + 3) * LDT + kk] = f2bf(v.w);
        } else {
          us4 v = *(const us4*)((const u16*)Bp + (long)bz * sB + (long)(k0 + kk) * ldB + n0 + nv * 4);
#pragma unroll
          for (int j = 0; j < 4; ++j) Bsm[(nv * 4 + j) * LDT + kk] = v[j];
        }
      }
    }
    __syncthreads();
#pragma unroll
    for (int kk = 0; kk < 2; ++kk) {
      const int ko = kk * 32 + lhi * 8;
      s8v a = *(const s8v*)&Asm[(wv * 16 + llo) * LDT + ko];
#pragma unroll
      for (int nf = 0; nf < 4; ++nf) {
        s8v b = *(const s8v*)&Bsm[(nf * 16 + llo) * LDT + ko];
        acc[nf] = __builtin_amdgcn_mfma_f32_16x16x32_bf16(a, b, acc[nf], 0, 0, 0);
      }
    }
  }
#pragma unroll
  for (int nf = 0; nf < 4; ++nf) {
    const int col = n0 + nf * 16 + llo;
    float bn_ = (BIAS == 2) ? bias[col] : 0.f;
#pragma unroll
    for (int r = 0; r < 4; ++r) {
      const int row = m0 + wv * 16 + lhi * 4 + r;
      float val = acc[nf][r] * alpha + bn_;
      if (BIAS == 1) val += bias[row];
      long off = (long)bz * sD + (long)row * ldD + col;
      if (RES) val += resid[(long)bz * sRes + (long)row * ldD + col];
      if (OUTM == 0)      ((float*)Dp)[off] = val;
      else if (OUTM == 1) ((float*)Dp)[off] += val;
      else                ((u16*)Dp)[off] = f2bf(val);
    }
  }
}

// ---------------- temporal axial attention: block per (b,hw), 8 heads, T=16 -------
__global__ __launch_bounds__(256) void tattn_kernel(const u16* __restrict__ qt,
                                                    const u16* __restrict__ kt,
                                                    const u16* __restrict__ vt,
                                                    u16* __restrict__ ot) {
  const int bi = blockIdx.x >> 10, hw = blockIdx.x & 1023;
  const long base = (long)bi * 4194304 + (long)hw * 256;
  __shared__ float qs[16][260], ks[16][260], vs[16][260];
  __shared__ u16 os[16][256];
  const int tid = threadIdx.x;
#pragma unroll
  for (int it = 0; it < 4; ++it) {
    int idx = it * 256 + tid;
    int t = idx >> 6, cv = idx & 63;
    long g = base + (long)t * 262144 + cv * 4;
    us4 a = *(const us4*)(qt + g);
    us4 b = *(const us4*)(kt + g);
    us4 c = *(const us4*)(vt + g);
#pragma unroll
    for (int j = 0; j < 4; ++j) {
      qs[t][cv * 4 + j] = bf2f(a[j]);
      ks[t][cv * 4 + j] = bf2f(b[j]);
      vs[t][cv * 4 + j] = bf2f(c[j]);
    }
  }
  __syncthreads();
  if (tid < 128) {
    const int h = tid >> 4, t = tid & 15;
    const int c0 = h * 32;
    float sc[16];
    float mx = -3.4e38f;
#pragma unroll
    for (int t2 = 0; t2 < 16; ++t2) {
      float d = 0.f;
#pragma unroll
      for (int dd = 0; dd < 32; ++dd) d += qs[t][c0 + dd] * ks[t2][c0 + dd];
      sc[t2] = d * 0.17677669529663687f;
      mx = fmaxf(mx, sc[t2]);
    }
    float sum = 0.f;
#pragma unroll
    for (int t2 = 0; t2 < 16; ++t2) { sc[t2] = __expf(sc[t2] - mx); sum += sc[t2]; }
    float inv = 1.f / sum;
#pragma unroll
    for (int dd = 0; dd < 32; ++dd) {
      float o = 0.f;
#pragma unroll
      for (int t2 = 0; t2 < 16; ++t2) o += sc[t2] * vs[t2][c0 + dd];
      os[t][c0 + dd] = f2bf(o * inv);
    }
  }
  __syncthreads();
#pragma unroll
  for (int it = 0; it < 4; ++it) {
    int idx = it * 256 + tid;
    int t = idx >> 6, cv = idx & 63;
    us4 o4;
#pragma unroll
    for (int j = 0; j < 4; ++j) o4[j] = os[t][cv * 4 + j];
    *(us4*)(ot + base + (long)t * 262144 + cv * 4) = o4;
  }
}

// =================================================================================
extern "C" void kernel_launch(void* const* d_in, const int* in_sizes, int n_in,
                              void* d_out, int out_size, void* d_ws, size_t ws_size,
                              hipStream_t stream) {
  const float* x     = (const float*)d_in[0];
  const float* gam   = (const float*)d_in[1];
  const float* bet   = (const float*)d_in[2];
  const float* wq_s  = (const float*)d_in[3];
  const float* bq_s  = (const float*)d_in[4];
  const float* wk_s  = (const float*)d_in[5];
  const float* bk_s  = (const float*)d_in[6];
  const float* wv_s  = (const float*)d_in[7];
  const float* bv_s  = (const float*)d_in[8];
  const float* wo_s  = (const float*)d_in[9];
  const float* bo_s  = (const float*)d_in[10];
  const float* wq_t  = (const float*)d_in[11];
  const float* wk_t  = (const float*)d_in[12];
  const float* wv_t  = (const float*)d_in[13];
  const float* wf_t  = (const float*)d_in[14];
  const float* bf_t  = (const float*)d_in[15];
  float* out = (float*)d_out;

  u16* qb   = (u16*)d_ws;           // [32][1024][256]
  u16* kb   = qb + 8388608;         // [32][1024][256]
  u16* vb   = kb + 8388608;         // [32][256][1024]
  u16* attb = vb + 8388608;         // [32][1024][256]
  float2* stats = (float2*)(attb + 8388608);
  u16* qt = qb; u16* kt = kb; u16* vt = vb; u16* ot = attb;  // temporal aliases

  gn_stats_kernel<<<1024, 256, 0, stream>>>(x, stats);
  qkv_s_kernel<<<dim3(4, 16, 32), 256, 0, stream>>>(x, stats, gam, bet,
      wq_s, bq_s, wk_s, bk_s, wv_s, bv_s, qb, kb, vb);
  flash_kernel<<<256, 512, 0, stream>>>(qb, kb, vb, attb);
  // proj: out[n][o][p] = x + bo[o] + wo[o][c] . att[p][c]  (f32 out, residual)
  gemm_kernel<1,0,0,0,1,1,0><<<dim3(16,4,32),256,0,stream>>>(wo_s, attb, bo_s, x, out, 256, 256, 0L, 256, 262144L, 1024, 262144L, 262144L, 1.f);
  qkv_t_kernel<<<dim3(4, 256, 2), 256, 0, stream>>>(x, wq_t, wk_t, wv_t, qt, kt, vt);
  tattn_kernel<<<2048, 256, 0, stream>>>(qt, kt, vt, ot);
  // final: out[b][o][s] += bf[o] + wf_t[c][o] . ot[s][c]  (f32 accumulate)
  gemm_kernel<1,1,0,0,1,0,1><<<dim3(256,4,2),256,0,stream>>>(wf_t, ot, bf_t, nullptr, out, 256, 256, 0L, 256, 4194304L, 16384, 4194304L, 0L, 1.f);
}

// Round 4
// 207.199 us; speedup vs baseline: 2.9025x; 1.7058x over previous
//
#include <hip/hip_runtime.h>
#include <stdint.h>

typedef uint16_t u16;
typedef __attribute__((ext_vector_type(8))) short s8v;      // 8 x bf16 MFMA frag
typedef __attribute__((ext_vector_type(4))) float f32x4;
typedef __attribute__((ext_vector_type(4))) unsigned short us4;

__device__ __forceinline__ float bf2f(u16 u) {
  union { uint32_t i; float f; } x; x.i = ((uint32_t)u) << 16; return x.f;
}
__device__ __forceinline__ u16 f2bf(float f) {
  union { float f; uint32_t i; } x; x.f = f;
  uint32_t r = (x.i + 0x7FFFu + ((x.i >> 16) & 1u)) >> 16;
  return (u16)r;
}
__device__ __forceinline__ void gl2lds16(const u16* g, u16* l) {
  __builtin_amdgcn_global_load_lds(
      (const __attribute__((address_space(1))) uint32_t*)g,
      (__attribute__((address_space(3))) uint32_t*)l, 16, 0, 0);
}

// ---------------- GroupNorm stats: one block per (n,g), 8192 contiguous floats ----
__global__ __launch_bounds__(256) void gn_stats_kernel(const float* __restrict__ x,
                                                       float2* __restrict__ stats) {
  const int tid = threadIdx.x;
  const float* p = x + (long)blockIdx.x * 8192;
  float s = 0.f, s2 = 0.f;
#pragma unroll
  for (int it = 0; it < 8; ++it) {
    float4 v = *(const float4*)(p + it * 1024 + tid * 4);
    s  += v.x + v.y + v.z + v.w;
    s2 += v.x * v.x + v.y * v.y + v.z * v.z + v.w * v.w;
  }
#pragma unroll
  for (int off = 32; off >= 1; off >>= 1) {
    s  += __shfl_down(s, off);
    s2 += __shfl_down(s2, off);
  }
  __shared__ float ps[4], ps2[4];
  const int wv = tid >> 6, lane = tid & 63;
  if (lane == 0) { ps[wv] = s; ps2[wv] = s2; }
  __syncthreads();
  if (tid == 0) {
    float S1 = ps[0] + ps[1] + ps[2] + ps[3];
    float S2 = ps2[0] + ps2[1] + ps2[2] + ps2[3];
    float mean = S1 * (1.f / 8192.f);
    float var = S2 * (1.f / 8192.f) - mean * mean;
    stats[blockIdx.x] = make_float2(mean, rsqrtf(var + 1e-6f));
  }
}

// ---------------- weight prep: bf16 copies [o][c]; mats 4..7 transposed -----------
__global__ __launch_bounds__(256) void wprep_kernel(
    const float* __restrict__ s0, const float* __restrict__ s1,
    const float* __restrict__ s2, const float* __restrict__ s3,
    const float* __restrict__ s4, const float* __restrict__ s5,
    const float* __restrict__ s6, const float* __restrict__ s7,
    u16* __restrict__ wbf) {
  const int mat = blockIdx.x, rb = blockIdx.y;
  const float* src = mat==0?s0:mat==1?s1:mat==2?s2:mat==3?s3:mat==4?s4:mat==5?s5:mat==6?s6:s7;
  u16* dst = wbf + mat * 65536 + rb * 16384;
  const int tid = threadIdx.x;
  if (mat < 4) {
    const float* sb = src + rb * 16384;
#pragma unroll
    for (int it = 0; it < 16; ++it) {
      int idx = it * 256 + tid;
      float4 v = *(const float4*)(sb + idx * 4);
      us4 o; o[0]=f2bf(v.x); o[1]=f2bf(v.y); o[2]=f2bf(v.z); o[3]=f2bf(v.w);
      *(us4*)(dst + idx * 4) = o;
    }
  } else {
    __shared__ u16 tl[64][264];
#pragma unroll
    for (int it = 0; it < 16; ++it) {
      int idx = it * 256 + tid;
      int c = idx >> 4, o4 = idx & 15;
      float4 v = *(const float4*)(src + c * 256 + rb * 64 + o4 * 4);
      tl[o4*4+0][c] = f2bf(v.x);
      tl[o4*4+1][c] = f2bf(v.y);
      tl[o4*4+2][c] = f2bf(v.z);
      tl[o4*4+3][c] = f2bf(v.w);
    }
    __syncthreads();
#pragma unroll
    for (int it = 0; it < 16; ++it) {
      int idx = it * 256 + tid;
      int o = idx >> 6, c4 = idx & 63;
      us4 u;
#pragma unroll
      for (int j = 0; j < 4; ++j) u[j] = tl[o][c4*4+j];
      *(us4*)(dst + o * 256 + c4 * 4) = u;
    }
  }
}

// ---------------- fused spatial GN + q/k/v GEMM v3 --------------------------------
// 256 blocks (32 n x 8 ptiles of 128 rows), 8 waves; A in regs, W dbuf via gl2lds
__global__ __launch_bounds__(512) void qkv_s_kernel(
    const float* __restrict__ x, const float2* __restrict__ stats,
    const float* __restrict__ gamma, const float* __restrict__ beta,
    const u16* __restrict__ wbf,
    const float* __restrict__ bq, const float* __restrict__ bk, const float* __restrict__ bv,
    u16* __restrict__ qb, u16* __restrict__ kb, u16* __restrict__ vb) {
  __shared__ float gas[256], bes[256];
  __shared__ u16 ALDS[128 * 256];
  __shared__ u16 WLDS[2][64 * 256];
  const int bid = blockIdx.x;
  const int n = bid >> 3, pt = bid & 7;
  const int p0 = pt * 128;
  const int tid = threadIdx.x, w = tid >> 6, lane = tid & 63;
  const int lhi = lane >> 4, llo = lane & 15;
  const long nbase = (long)n * 262144;

  if (tid < 256) {
    float2 st = stats[n * 32 + (tid >> 3)];
    float ga = gamma[tid] * st.y;
    gas[tid] = ga;
    bes[tid] = beta[tid] - st.x * ga;
  }
  __syncthreads();

  const float* xb = x + nbase + p0;
#pragma unroll
  for (int it = 0; it < 16; ++it) {
    int idx = it * 512 + tid;
    int p = idx & 127, c4 = idx >> 7;
    us4 o;
#pragma unroll
    for (int j = 0; j < 4; ++j) {
      int c = c4 * 4 + j;
      float v = xb[(long)c * 1024 + p];
      o[j] = f2bf(v * gas[c] + bes[c]);
    }
    int ch = c4 >> 1;
    *(us4*)&ALDS[p * 256 + ((ch ^ (p & 7)) << 3) + ((c4 & 1) << 2)] = o;
  }
  __syncthreads();

  const int arow = w * 16 + llo;
  s8v qa[8];
#pragma unroll
  for (int kk = 0; kk < 8; ++kk)
    qa[kk] = *(const s8v*)&ALDS[arow * 256 + (((kk * 4 + lhi) ^ (arow & 7)) << 3)];

  auto stageW = [&](int t, int bu) {
    const u16* wsrc = wbf + (t >> 2) * 65536 + (long)(t & 3) * 16384;
#pragma unroll
    for (int ii = 0; ii < 4; ++ii) {
      int i0 = (w * 4 + ii) * 64;
      int g = i0 + lane;
      int row = g >> 5, ch = g & 31;
      gl2lds16(wsrc + row * 256 + ((ch ^ (row & 7)) << 3), &WLDS[bu][i0 * 8]);
    }
  };

  stageW(0, 0);
  __syncthreads();

  u16* vtl = ALDS;  // reuse for v transpose [64 o][136]
  for (int t = 0; t < 12; ++t) {
    const int cur = t & 1;
    if (t < 11) stageW(t + 1, cur ^ 1);
    f32x4 acc[4] = {};
#pragma unroll
    for (int kk = 0; kk < 8; ++kk)
#pragma unroll
      for (int nf = 0; nf < 4; ++nf) {
        int row = nf * 16 + llo;
        s8v bfr = *(const s8v*)&WLDS[cur][row * 256 + (((kk * 4 + lhi) ^ (row & 7)) << 3)];
        acc[nf] = __builtin_amdgcn_mfma_f32_16x16x32_bf16(qa[kk], bfr, acc[nf], 0, 0, 0);
      }
    const int o0 = (t & 3) * 64;
    if (t < 8) {
      u16* dstb = (t < 4) ? qb : kb;
      const float* bias = (t < 4) ? bq : bk;
#pragma unroll
      for (int nf = 0; nf < 4; ++nf) {
        int o = o0 + nf * 16 + llo;
        float b_ = bias[o];
#pragma unroll
        for (int r = 0; r < 4; ++r)
          dstb[nbase + (long)(p0 + w * 16 + lhi * 4 + r) * 256 + o] = f2bf(acc[nf][r] + b_);
      }
    } else {
#pragma unroll
      for (int nf = 0; nf < 4; ++nf) {
        int o = nf * 16 + llo;
        float b_ = bv[o0 + o];
#pragma unroll
        for (int r = 0; r < 4; ++r)
          vtl[o * 136 + w * 16 + lhi * 4 + r] = f2bf(acc[nf][r] + b_);
      }
      __syncthreads();
#pragma unroll
      for (int ii = 0; ii < 4; ++ii) {
        int i = ii * 512 + tid;
        int o = i >> 5, p4 = (i & 31) * 4;
        us4 u;
#pragma unroll
        for (int j = 0; j < 4; ++j) u[j] = vtl[o * 136 + p4 + j];
        *(us4*)(vb + nbase + (long)(o0 + o) * 1024 + p0 + p4) = u;
      }
    }
    __syncthreads();
  }
}

// ---------------- flash spatial attention (unchanged from r3) ----------------------
__global__ __launch_bounds__(512, 2) void flash_kernel(const u16* __restrict__ qb,
                                                       const u16* __restrict__ kb,
                                                       const u16* __restrict__ vb,
                                                       u16* __restrict__ attb) {
  const int wg = blockIdx.x;
  const int swz = (wg & 7) * 32 + (wg >> 3);
  const int n = swz >> 3, qt = swz & 7;
  const int tid = threadIdx.x, wid = tid >> 6, lane = tid & 63;
  const int lhi = lane >> 4, llo = lane & 15;
  const long nbase = (long)n * 262144;

  __shared__ u16 Kb[2][64 * 256];
  __shared__ u16 Vb[2][256 * 64];
  __shared__ u16 ps[128][72];

  const u16* qrow = qb + nbase + (long)(qt * 128 + wid * 16 + llo) * 256;
  s8v qa[8];
#pragma unroll
  for (int kk = 0; kk < 8; ++kk) qa[kk] = *(const s8v*)(qrow + kk * 32 + lhi * 8);

  f32x4 oacc[16] = {};
  float m_[4], l_[4];
#pragma unroll
  for (int r = 0; r < 4; ++r) { m_[r] = -3.4e38f; l_[r] = 0.f; }

  const int l5 = lane >> 5, c16 = lane & 31, l3 = lane >> 3, ch8 = lane & 7;

  auto stageKV = [&](int jt2, int b) {
    const u16* kbase = kb + nbase + (long)jt2 * 64 * 256;
    const u16* vbase = vb + nbase + (long)jt2 * 64;
#pragma unroll
    for (int ii = 0; ii < 4; ++ii) {
      int i = wid * 4 + ii;
      int r = i * 2 + l5;
      gl2lds16(kbase + (long)r * 256 + ((c16 ^ (r & 7)) * 8), &Kb[b][i * 512]);
    }
#pragma unroll
    for (int ii = 0; ii < 4; ++ii) {
      int i = wid * 4 + ii;
      int c = i * 8 + l3;
      gl2lds16(vbase + (long)c * 1024 + ((ch8 ^ (c & 7)) * 8), &Vb[b][i * 512]);
    }
  };

  stageKV(0, 0);
  __syncthreads();

  for (int jt = 0; jt < 16; ++jt) {
    const int cur = jt & 1;
    if (jt < 15) stageKV(jt + 1, cur ^ 1);

    f32x4 sacc[4] = {};
#pragma unroll
    for (int jf = 0; jf < 4; ++jf) {
      const int row = jf * 16 + llo;
      const u16* kr = &Kb[cur][row * 256];
#pragma unroll
      for (int kk = 0; kk < 8; ++kk) {
        const int chunk = (kk * 4 + lhi) ^ (row & 7);
        s8v b = *(const s8v*)(kr + chunk * 8);
        sacc[jf] = __builtin_amdgcn_mfma_f32_16x16x32_bf16(qa[kk], b, sacc[jf], 0, 0, 0);
      }
    }
#pragma unroll
    for (int jf = 0; jf < 4; ++jf)
#pragma unroll
      for (int r = 0; r < 4; ++r) sacc[jf][r] *= 0.0625f;
    float sc[4];
#pragma unroll
    for (int r = 0; r < 4; ++r) {
      float mx = fmaxf(fmaxf(sacc[0][r], sacc[1][r]), fmaxf(sacc[2][r], sacc[3][r]));
      mx = fmaxf(mx, __shfl_xor(mx, 1));
      mx = fmaxf(mx, __shfl_xor(mx, 2));
      mx = fmaxf(mx, __shfl_xor(mx, 4));
      mx = fmaxf(mx, __shfl_xor(mx, 8));
      float nm = fmaxf(m_[r], mx);
      sc[r] = __expf(m_[r] - nm);
      m_[r] = nm;
    }
    float rs[4] = {0.f, 0.f, 0.f, 0.f};
#pragma unroll
    for (int jf = 0; jf < 4; ++jf)
#pragma unroll
      for (int r = 0; r < 4; ++r) {
        float p = __expf(sacc[jf][r] - m_[r]);
        rs[r] += p;
        ps[wid * 16 + lhi * 4 + r][jf * 16 + llo] = f2bf(p);
      }
#pragma unroll
    for (int r = 0; r < 4; ++r) {
      rs[r] += __shfl_xor(rs[r], 1);
      rs[r] += __shfl_xor(rs[r], 2);
      rs[r] += __shfl_xor(rs[r], 4);
      rs[r] += __shfl_xor(rs[r], 8);
      l_[r] = l_[r] * sc[r] + rs[r];
    }
#pragma unroll
    for (int cf = 0; cf < 16; ++cf)
#pragma unroll
      for (int r = 0; r < 4; ++r) oacc[cf][r] *= sc[r];
    s8v pa[2];
#pragma unroll
    for (int kk = 0; kk < 2; ++kk)
      pa[kk] = *(const s8v*)&ps[wid * 16 + llo][kk * 32 + lhi * 8];
#pragma unroll
    for (int cf = 0; cf < 16; ++cf) {
      const int c = cf * 16 + llo;
      const u16* vr = &Vb[cur][c * 64];
#pragma unroll
      for (int kk = 0; kk < 2; ++kk) {
        const int chunk = (kk * 4 + lhi) ^ (c & 7);
        s8v b = *(const s8v*)(vr + chunk * 8);
        oacc[cf] = __builtin_amdgcn_mfma_f32_16x16x32_bf16(pa[kk], b, oacc[cf], 0, 0, 0);
      }
    }
    __syncthreads();
  }
  u16* obase = attb + nbase + (long)(qt * 128 + wid * 16) * 256;
#pragma unroll
  for (int r = 0; r < 4; ++r) {
    float inv = 1.f / l_[r];
#pragma unroll
    for (int cf = 0; cf < 16; ++cf)
      obase[(lhi * 4 + r) * 256 + cf * 16 + llo] = f2bf(oacc[cf][r] * inv);
  }
}

// ---------------- fused temporal q/k/v GEMM v2 -------------------------------------
__global__ __launch_bounds__(512) void qkv_t_kernel(
    const float* __restrict__ x, const u16* __restrict__ wbf,
    u16* __restrict__ qt, u16* __restrict__ kt, u16* __restrict__ vt) {
  __shared__ u16 ALDS[128 * 256];
  __shared__ u16 WLDS[2][64 * 256];
  const int bid = blockIdx.x;
  const int b = bid >> 7, st = bid & 127;
  const int s0 = st * 128;
  const int tid = threadIdx.x, w = tid >> 6, lane = tid & 63;
  const int lhi = lane >> 4, llo = lane & 15;
  const long bbase = (long)b * 4194304;

  const float* xb = x + bbase + s0;
#pragma unroll
  for (int it = 0; it < 16; ++it) {
    int idx = it * 512 + tid;
    int p = idx & 127, c4 = idx >> 7;
    us4 o;
#pragma unroll
    for (int j = 0; j < 4; ++j)
      o[j] = f2bf(xb[(long)(c4 * 4 + j) * 16384 + p]);
    int ch = c4 >> 1;
    *(us4*)&ALDS[p * 256 + ((ch ^ (p & 7)) << 3) + ((c4 & 1) << 2)] = o;
  }
  __syncthreads();
  const int arow = w * 16 + llo;
  s8v qa[8];
#pragma unroll
  for (int kk = 0; kk < 8; ++kk)
    qa[kk] = *(const s8v*)&ALDS[arow * 256 + (((kk * 4 + lhi) ^ (arow & 7)) << 3)];

  auto stageW = [&](int t, int bu) {
    const u16* wsrc = wbf + (4 + (t >> 2)) * 65536 + (long)(t & 3) * 16384;
#pragma unroll
    for (int ii = 0; ii < 4; ++ii) {
      int i0 = (w * 4 + ii) * 64;
      int g = i0 + lane;
      int row = g >> 5, ch = g & 31;
      gl2lds16(wsrc + row * 256 + ((ch ^ (row & 7)) << 3), &WLDS[bu][i0 * 8]);
    }
  };
  stageW(0, 0);
  __syncthreads();
  for (int t = 0; t < 12; ++t) {
    const int cur = t & 1;
    if (t < 11) stageW(t + 1, cur ^ 1);
    f32x4 acc[4] = {};
#pragma unroll
    for (int kk = 0; kk < 8; ++kk)
#pragma unroll
      for (int nf = 0; nf < 4; ++nf) {
        int row = nf * 16 + llo;
        s8v bb = *(const s8v*)&WLDS[cur][row * 256 + (((kk * 4 + lhi) ^ (row & 7)) << 3)];
        acc[nf] = __builtin_amdgcn_mfma_f32_16x16x32_bf16(qa[kk], bb, acc[nf], 0, 0, 0);
      }
    u16* dstb = (t < 4) ? qt : (t < 8) ? kt : vt;
    const int o0 = (t & 3) * 64;
#pragma unroll
    for (int nf = 0; nf < 4; ++nf) {
      int o = o0 + nf * 16 + llo;
#pragma unroll
      for (int r = 0; r < 4; ++r)
        dstb[bbase + (long)(s0 + w * 16 + lhi * 4 + r) * 256 + o] = f2bf(acc[nf][r]);
    }
    __syncthreads();
  }
}

// ---------------- temporal axial attention (unchanged) -----------------------------
__global__ __launch_bounds__(256) void tattn_kernel(const u16* __restrict__ qt,
                                                    const u16* __restrict__ kt,
                                                    const u16* __restrict__ vt,
                                                    u16* __restrict__ ot) {
  const int bi = blockIdx.x >> 10, hw = blockIdx.x & 1023;
  const long base = (long)bi * 4194304 + (long)hw * 256;
  __shared__ float qs[16][260], ks[16][260], vs[16][260];
  __shared__ u16 os[16][256];
  const int tid = threadIdx.x;
#pragma unroll
  for (int it = 0; it < 4; ++it) {
    int idx = it * 256 + tid;
    int t = idx >> 6, cv = idx & 63;
    long g = base + (long)t * 262144 + cv * 4;
    us4 a = *(const us4*)(qt + g);
    us4 b = *(const us4*)(kt + g);
    us4 c = *(const us4*)(vt + g);
#pragma unroll
    for (int j = 0; j < 4; ++j) {
      qs[t][cv * 4 + j] = bf2f(a[j]);
      ks[t][cv * 4 + j] = bf2f(b[j]);
      vs[t][cv * 4 + j] = bf2f(c[j]);
    }
  }
  __syncthreads();
  if (tid < 128) {
    const int h = tid >> 4, t = tid & 15;
    const int c0 = h * 32;
    float sc[16];
    float mx = -3.4e38f;
#pragma unroll
    for (int t2 = 0; t2 < 16; ++t2) {
      float d = 0.f;
#pragma unroll
      for (int dd = 0; dd < 32; ++dd) d += qs[t][c0 + dd] * ks[t2][c0 + dd];
      sc[t2] = d * 0.17677669529663687f;
      mx = fmaxf(mx, sc[t2]);
    }
    float sum = 0.f;
#pragma unroll
    for (int t2 = 0; t2 < 16; ++t2) { sc[t2] = __expf(sc[t2] - mx); sum += sc[t2]; }
    float inv = 1.f / sum;
#pragma unroll
    for (int dd = 0; dd < 32; ++dd) {
      float o = 0.f;
#pragma unroll
      for (int t2 = 0; t2 < 16; ++t2) o += sc[t2] * vs[t2][c0 + dd];
      os[t][c0 + dd] = f2bf(o * inv);
    }
  }
  __syncthreads();
#pragma unroll
  for (int it = 0; it < 4; ++it) {
    int idx = it * 256 + tid;
    int t = idx >> 6, cv = idx & 63;
    us4 o4;
#pragma unroll
    for (int j = 0; j < 4; ++j) o4[j] = os[t][cv * 4 + j];
    *(us4*)(ot + base + (long)t * 262144 + cv * 4) = o4;
  }
}

// ---------------- temporal final projection -> tmpT[b][co][s] bf16 -----------------
__global__ __launch_bounds__(512) void tfinal_kernel(
    const u16* __restrict__ ott, const u16* __restrict__ wbf,
    u16* __restrict__ tmpT) {
  __shared__ u16 ALDS[128 * 256];
  __shared__ u16 WLDS[2][64 * 256];
  const int bid = blockIdx.x;
  const int b = bid >> 7, st = bid & 127;
  const int s0 = st * 128;
  const int tid = threadIdx.x, w = tid >> 6, lane = tid & 63;
  const int lhi = lane >> 4, llo = lane & 15;
  const long bbase = (long)b * 4194304;

  const u16* otS = ott + bbase + (long)s0 * 256;
#pragma unroll
  for (int ii = 0; ii < 8; ++ii) {
    int i0 = (w * 8 + ii) * 64;
    int g = i0 + lane;
    int row = g >> 5, ch = g & 31;
    gl2lds16(otS + row * 256 + ((ch ^ (row & 7)) << 3), &ALDS[i0 * 8]);
  }
  __syncthreads();
  const int arow = w * 16 + llo;
  s8v qa[8];
#pragma unroll
  for (int kk = 0; kk < 8; ++kk)
    qa[kk] = *(const s8v*)&ALDS[arow * 256 + (((kk * 4 + lhi) ^ (arow & 7)) << 3)];

  auto stageW = [&](int t, int bu) {
    const u16* wsrc = wbf + 7 * 65536 + (long)t * 16384;
#pragma unroll
    for (int ii = 0; ii < 4; ++ii) {
      int i0 = (w * 4 + ii) * 64;
      int g = i0 + lane;
      int row = g >> 5, ch = g & 31;
      gl2lds16(wsrc + row * 256 + ((ch ^ (row & 7)) << 3), &WLDS[bu][i0 * 8]);
    }
  };
  stageW(0, 0);
  __syncthreads();
  u16* vtl = ALDS;  // safe: frags already in regs
  for (int t = 0; t < 4; ++t) {
    const int cur = t & 1;
    if (t < 3) stageW(t + 1, cur ^ 1);
    f32x4 acc[4] = {};
#pragma unroll
    for (int kk = 0; kk < 8; ++kk)
#pragma unroll
      for (int nf = 0; nf < 4; ++nf) {
        int row = nf * 16 + llo;
        s8v bb = *(const s8v*)&WLDS[cur][row * 256 + (((kk * 4 + lhi) ^ (row & 7)) << 3)];
        acc[nf] = __builtin_amdgcn_mfma_f32_16x16x32_bf16(qa[kk], bb, acc[nf], 0, 0, 0);
      }
#pragma unroll
    for (int nf = 0; nf < 4; ++nf) {
      int o = nf * 16 + llo;
#pragma unroll
      for (int r = 0; r < 4; ++r)
        vtl[o * 136 + w * 16 + lhi * 4 + r] = f2bf(acc[nf][r]);
    }
    __syncthreads();
    const int o0 = t * 64;
#pragma unroll
    for (int ii = 0; ii < 4; ++ii) {
      int i = ii * 512 + tid;
      int o = i >> 5, p4 = (i & 31) * 4;
      us4 uu;
#pragma unroll
      for (int j = 0; j < 4; ++j) uu[j] = vtl[o * 136 + p4 + j];
      *(us4*)(tmpT + bbase + (long)(o0 + o) * 16384 + s0 + p4) = uu;
    }
    __syncthreads();
  }
}

// ---------------- fused output: out = x + bo + bf + wo.att + tmpT ------------------
__global__ __launch_bounds__(256) void outproj_kernel(
    const float* __restrict__ x, const u16* __restrict__ attb,
    const u16* __restrict__ tmpT, const u16* __restrict__ wbf,
    const float* __restrict__ bo, const float* __restrict__ bf,
    float* __restrict__ out) {
  __shared__ u16 attL[64 * 256];
  const int u = blockIdx.x;
  const int wkx = (u & 7) * 256 + (u >> 3);  // XCD-chunk swizzle (2048 % 8 == 0)
  const int otile = wkx & 3, pt = (wkx >> 2) & 15, n = wkx >> 6;
  const int b = n >> 4;
  const int o0 = otile * 64, p0 = pt * 64;
  const int tid = threadIdx.x, w = tid >> 6, lane = tid & 63;
  const int lhi = lane >> 4, llo = lane & 15;
  const long nbase = (long)n * 262144;

  const u16* attS = attb + nbase + (long)p0 * 256;
#pragma unroll
  for (int ii = 0; ii < 8; ++ii) {
    int i0 = (w * 8 + ii) * 64;
    int g = i0 + lane;
    int row = g >> 5, ch = g & 31;
    gl2lds16(attS + row * 256 + ((ch ^ (row & 7)) << 3), &attL[i0 * 8]);
  }
  const u16* woR = wbf + 3 * 65536 + (long)(o0 + w * 16 + llo) * 256;
  s8v woa[8];
#pragma unroll
  for (int kk = 0; kk < 8; ++kk)
    woa[kk] = *(const s8v*)(woR + kk * 32 + lhi * 8);
  __syncthreads();
  f32x4 acc[4] = {};
#pragma unroll
  for (int kk = 0; kk < 8; ++kk)
#pragma unroll
    for (int nf = 0; nf < 4; ++nf) {
      int row = nf * 16 + llo;
      s8v b1 = *(const s8v*)&attL[row * 256 + (((kk * 4 + lhi) ^ (row & 7)) << 3)];
      acc[nf] = __builtin_amdgcn_mfma_f32_16x16x32_bf16(woa[kk], b1, acc[nf], 0, 0, 0);
    }
#pragma unroll
  for (int r = 0; r < 4; ++r) {
    int cp = o0 + w * 16 + lhi * 4 + r;          // output channel c'
    int co = ((n & 15) << 4) + (cp >> 4);        // temporal channel
    int tt = cp & 15;                            // temporal t
    float bias = bo[cp] + bf[co];
    const u16* tr = tmpT + (long)b * 4194304 + (long)co * 16384 + tt * 1024 + p0;
    const float* xr = x + nbase + (long)cp * 1024 + p0;
    float* orow = out + nbase + (long)cp * 1024 + p0;
#pragma unroll
    for (int nf = 0; nf < 4; ++nf) {
      int p = nf * 16 + llo;
      orow[p] = acc[nf][r] + bias + xr[p] + bf2f(tr[p]);
    }
  }
}

// =================================================================================
extern "C" void kernel_launch(void* const* d_in, const int* in_sizes, int n_in,
                              void* d_out, int out_size, void* d_ws, size_t ws_size,
                              hipStream_t stream) {
  const float* x     = (const float*)d_in[0];
  const float* gam   = (const float*)d_in[1];
  const float* bet   = (const float*)d_in[2];
  const float* wq_s  = (const float*)d_in[3];
  const float* bq_s  = (const float*)d_in[4];
  const float* wk_s  = (const float*)d_in[5];
  const float* bk_s  = (const float*)d_in[6];
  const float* wv_s  = (const float*)d_in[7];
  const float* bv_s  = (const float*)d_in[8];
  const float* wo_s  = (const float*)d_in[9];
  const float* bo_s  = (const float*)d_in[10];
  const float* wq_t  = (const float*)d_in[11];
  const float* wk_t  = (const float*)d_in[12];
  const float* wv_t  = (const float*)d_in[13];
  const float* wf_t  = (const float*)d_in[14];
  const float* bf_t  = (const float*)d_in[15];
  float* out = (float*)d_out;

  u16* qb   = (u16*)d_ws;           // [32][1024][256]
  u16* kb   = qb + 8388608;         // [32][1024][256]
  u16* vb   = kb + 8388608;         // [32][256][1024]
  u16* attb = vb + 8388608;         // [32][1024][256]
  u16* ottb = attb + 8388608;       // [2][16384][256]
  u16* wbf  = ottb + 8388608;       // 8 x [256][256] bf16
  float2* stats = (float2*)(wbf + 524288);
  u16* qt = qb; u16* kt = kb; u16* vt = vb;   // temporal aliases (q/k/v dead post-flash)
  u16* tmpT = qb;                              // dead post-tattn

  gn_stats_kernel<<<1024, 256, 0, stream>>>(x, stats);
  wprep_kernel<<<dim3(8, 4), 256, 0, stream>>>(wq_s, wk_s, wv_s, wo_s,
                                               wq_t, wk_t, wv_t, wf_t, wbf);
  qkv_s_kernel<<<256, 512, 0, stream>>>(x, stats, gam, bet, wbf,
                                        bq_s, bk_s, bv_s, qb, kb, vb);
  flash_kernel<<<256, 512, 0, stream>>>(qb, kb, vb, attb);
  qkv_t_kernel<<<256, 512, 0, stream>>>(x, wbf, qt, kt, vt);
  tattn_kernel<<<2048, 256, 0, stream>>>(qt, kt, vt, ottb);
  tfinal_kernel<<<256, 512, 0, stream>>>(ottb, wbf, tmpT);
  outproj_kernel<<<2048, 256, 0, stream>>>(x, attb, tmpT, wbf, bo_s, bf_t, out);
}

// Round 5
// 202.986 us; speedup vs baseline: 2.9628x; 1.0208x over previous
//
#include <hip/hip_runtime.h>
#include <stdint.h>

typedef uint16_t u16;
typedef __attribute__((ext_vector_type(8))) short s8v;      // 8 x bf16 MFMA frag
typedef __attribute__((ext_vector_type(4))) float f32x4;
typedef __attribute__((ext_vector_type(16))) float f32x16;
typedef __attribute__((ext_vector_type(4))) unsigned short us4;
typedef __attribute__((ext_vector_type(4))) unsigned int u32x4;

__device__ __forceinline__ float bf2f(u16 u) {
  union { uint32_t i; float f; } x; x.i = ((uint32_t)u) << 16; return x.f;
}
__device__ __forceinline__ u16 f2bf(float f) {
  union { float f; uint32_t i; } x; x.f = f;
  uint32_t r = (x.i + 0x7FFFu + ((x.i >> 16) & 1u)) >> 16;
  return (u16)r;
}
__device__ __forceinline__ uint32_t cvtpk(float a, float b) {
  uint32_t r;
  asm("v_cvt_pk_bf16_f32 %0, %1, %2" : "=v"(r) : "v"(a), "v"(b));
  return r;
}
__device__ __forceinline__ void gl2lds16(const u16* g, u16* l) {
  __builtin_amdgcn_global_load_lds(
      (const __attribute__((address_space(1))) uint32_t*)g,
      (__attribute__((address_space(3))) uint32_t*)l, 16, 0, 0);
}

// ---------------- GroupNorm stats: one block per (n,g), 8192 contiguous floats ----
__global__ __launch_bounds__(256) void gn_stats_kernel(const float* __restrict__ x,
                                                       float2* __restrict__ stats) {
  const int tid = threadIdx.x;
  const float* p = x + (long)blockIdx.x * 8192;
  float s = 0.f, s2 = 0.f;
#pragma unroll
  for (int it = 0; it < 8; ++it) {
    float4 v = *(const float4*)(p + it * 1024 + tid * 4);
    s  += v.x + v.y + v.z + v.w;
    s2 += v.x * v.x + v.y * v.y + v.z * v.z + v.w * v.w;
  }
#pragma unroll
  for (int off = 32; off >= 1; off >>= 1) {
    s  += __shfl_down(s, off);
    s2 += __shfl_down(s2, off);
  }
  __shared__ float ps[4], ps2[4];
  const int wv = tid >> 6, lane = tid & 63;
  if (lane == 0) { ps[wv] = s; ps2[wv] = s2; }
  __syncthreads();
  if (tid == 0) {
    float S1 = ps[0] + ps[1] + ps[2] + ps[3];
    float S2 = ps2[0] + ps2[1] + ps2[2] + ps2[3];
    float mean = S1 * (1.f / 8192.f);
    float var = S2 * (1.f / 8192.f) - mean * mean;
    stats[blockIdx.x] = make_float2(mean, rsqrtf(var + 1e-6f));
  }
}

// ---------------- weight prep: bf16 copies [o][c]; mats 4..7 transposed -----------
__global__ __launch_bounds__(256) void wprep_kernel(
    const float* __restrict__ s0, const float* __restrict__ s1,
    const float* __restrict__ s2, const float* __restrict__ s3,
    const float* __restrict__ s4, const float* __restrict__ s5,
    const float* __restrict__ s6, const float* __restrict__ s7,
    u16* __restrict__ wbf) {
  const int mat = blockIdx.x, rb = blockIdx.y;
  const float* src = mat==0?s0:mat==1?s1:mat==2?s2:mat==3?s3:mat==4?s4:mat==5?s5:mat==6?s6:s7;
  u16* dst = wbf + mat * 65536 + rb * 16384;
  const int tid = threadIdx.x;
  if (mat < 4) {
    const float* sb = src + rb * 16384;
#pragma unroll
    for (int it = 0; it < 16; ++it) {
      int idx = it * 256 + tid;
      float4 v = *(const float4*)(sb + idx * 4);
      us4 o; o[0]=f2bf(v.x); o[1]=f2bf(v.y); o[2]=f2bf(v.z); o[3]=f2bf(v.w);
      *(us4*)(dst + idx * 4) = o;
    }
  } else {
    __shared__ u16 tl[64][264];
#pragma unroll
    for (int it = 0; it < 16; ++it) {
      int idx = it * 256 + tid;
      int c = idx >> 4, o4 = idx & 15;
      float4 v = *(const float4*)(src + c * 256 + rb * 64 + o4 * 4);
      tl[o4*4+0][c] = f2bf(v.x);
      tl[o4*4+1][c] = f2bf(v.y);
      tl[o4*4+2][c] = f2bf(v.z);
      tl[o4*4+3][c] = f2bf(v.w);
    }
    __syncthreads();
#pragma unroll
    for (int it = 0; it < 16; ++it) {
      int idx = it * 256 + tid;
      int o = idx >> 6, c4 = idx & 63;
      us4 u;
#pragma unroll
      for (int j = 0; j < 4; ++j) u[j] = tl[o][c4*4+j];
      *(us4*)(dst + o * 256 + c4 * 4) = u;
    }
  }
}

// ---------------- fused spatial GN + q/k/v GEMM v3 --------------------------------
__global__ __launch_bounds__(512) void qkv_s_kernel(
    const float* __restrict__ x, const float2* __restrict__ stats,
    const float* __restrict__ gamma, const float* __restrict__ beta,
    const u16* __restrict__ wbf,
    const float* __restrict__ bq, const float* __restrict__ bk, const float* __restrict__ bv,
    u16* __restrict__ qb, u16* __restrict__ kb, u16* __restrict__ vb) {
  __shared__ float gas[256], bes[256];
  __shared__ u16 ALDS[128 * 256];
  __shared__ u16 WLDS[2][64 * 256];
  const int bid = blockIdx.x;
  const int n = bid >> 3, pt = bid & 7;
  const int p0 = pt * 128;
  const int tid = threadIdx.x, w = tid >> 6, lane = tid & 63;
  const int lhi = lane >> 4, llo = lane & 15;
  const long nbase = (long)n * 262144;

  if (tid < 256) {
    float2 st = stats[n * 32 + (tid >> 3)];
    float ga = gamma[tid] * st.y;
    gas[tid] = ga;
    bes[tid] = beta[tid] - st.x * ga;
  }
  __syncthreads();

  const float* xb = x + nbase + p0;
#pragma unroll
  for (int it = 0; it < 16; ++it) {
    int idx = it * 512 + tid;
    int p = idx & 127, c4 = idx >> 7;
    us4 o;
#pragma unroll
    for (int j = 0; j < 4; ++j) {
      int c = c4 * 4 + j;
      float v = xb[(long)c * 1024 + p];
      o[j] = f2bf(v * gas[c] + bes[c]);
    }
    int ch = c4 >> 1;
    *(us4*)&ALDS[p * 256 + ((ch ^ (p & 7)) << 3) + ((c4 & 1) << 2)] = o;
  }
  __syncthreads();

  const int arow = w * 16 + llo;
  s8v qa[8];
#pragma unroll
  for (int kk = 0; kk < 8; ++kk)
    qa[kk] = *(const s8v*)&ALDS[arow * 256 + (((kk * 4 + lhi) ^ (arow & 7)) << 3)];

  auto stageW = [&](int t, int bu) {
    const u16* wsrc = wbf + (t >> 2) * 65536 + (long)(t & 3) * 16384;
#pragma unroll
    for (int ii = 0; ii < 4; ++ii) {
      int i0 = (w * 4 + ii) * 64;
      int g = i0 + lane;
      int row = g >> 5, ch = g & 31;
      gl2lds16(wsrc + row * 256 + ((ch ^ (row & 7)) << 3), &WLDS[bu][i0 * 8]);
    }
  };

  stageW(0, 0);
  __syncthreads();

  u16* vtl = ALDS;  // reuse for v transpose [64 o][136]
  for (int t = 0; t < 12; ++t) {
    const int cur = t & 1;
    if (t < 11) stageW(t + 1, cur ^ 1);
    f32x4 acc[4] = {};
#pragma unroll
    for (int kk = 0; kk < 8; ++kk)
#pragma unroll
      for (int nf = 0; nf < 4; ++nf) {
        int row = nf * 16 + llo;
        s8v bfr = *(const s8v*)&WLDS[cur][row * 256 + (((kk * 4 + lhi) ^ (row & 7)) << 3)];
        acc[nf] = __builtin_amdgcn_mfma_f32_16x16x32_bf16(qa[kk], bfr, acc[nf], 0, 0, 0);
      }
    const int o0 = (t & 3) * 64;
    if (t < 8) {
      u16* dstb = (t < 4) ? qb : kb;
      const float* bias = (t < 4) ? bq : bk;
#pragma unroll
      for (int nf = 0; nf < 4; ++nf) {
        int o = o0 + nf * 16 + llo;
        float b_ = bias[o];
#pragma unroll
        for (int r = 0; r < 4; ++r)
          dstb[nbase + (long)(p0 + w * 16 + lhi * 4 + r) * 256 + o] = f2bf(acc[nf][r] + b_);
      }
    } else {
#pragma unroll
      for (int nf = 0; nf < 4; ++nf) {
        int o = nf * 16 + llo;
        float b_ = bv[o0 + o];
#pragma unroll
        for (int r = 0; r < 4; ++r)
          vtl[o * 136 + w * 16 + lhi * 4 + r] = f2bf(acc[nf][r] + b_);
      }
      __syncthreads();
#pragma unroll
      for (int ii = 0; ii < 4; ++ii) {
        int i = ii * 512 + tid;
        int o = i >> 5, p4 = (i & 31) * 4;
        us4 u;
#pragma unroll
        for (int j = 0; j < 4; ++j) u[j] = vtl[o * 136 + p4 + j];
        *(us4*)(vb + nbase + (long)(o0 + o) * 1024 + p0 + p4) = u;
      }
    }
    __syncthreads();
  }
}

// ---------------- flash spatial attention v4 ---------------------------------------
// 256 blocks (32 n x 8 qtiles of 128 rows), 4 waves x 32 q-rows, 32x32x16 MFMA.
// Swapped QK^T (S^T), register softmax, in-register P redistribution, O^T accum.
__global__ __launch_bounds__(256, 1) void flash_kernel(const u16* __restrict__ qb,
                                                       const u16* __restrict__ kb,
                                                       const u16* __restrict__ vb,
                                                       u16* __restrict__ attb) {
  const int wg = blockIdx.x;
  const int swz = (wg & 7) * 32 + (wg >> 3);  // 4 n per XCD
  const int n = swz >> 3, qt = swz & 7;
  const int tid = threadIdx.x, w = tid >> 6, lane = tid & 63;
  const int q5 = lane & 31, h = lane >> 5;
  const long nbase = (long)n * 262144;

  __shared__ u16 Kb[2][64 * 256];  // [krow][c] 512B rows, chunk16 ^= (row&7)
  __shared__ u16 Vb[2][256 * 64];  // [c][j] 128B rows, chunk16 ^= (c&7)

  // Q fragments: B-operand, 32 q-rows per wave, k = kk*16 + h*8 + j
  const int qrow = qt * 128 + w * 32 + q5;
  const u16* qr = qb + nbase + (long)qrow * 256 + h * 8;
  s8v qa[16];
#pragma unroll
  for (int kk = 0; kk < 16; ++kk) qa[kk] = *(const s8v*)(qr + kk * 16);

  f32x16 oaccT[8] = {};   // O^T: c rows, q col (lane-uniform q)
  float m_ = -3.4e38f, l_ = 0.f;
  constexpr float CEXP = 0.09016844f;  // 0.0625 * log2(e)

  auto stageKV = [&](int jt2, int b) {
    const u16* kbase = kb + nbase + (long)jt2 * 64 * 256;
    const u16* vbase = vb + nbase + (long)jt2 * 64;
#pragma unroll
    for (int ii = 0; ii < 8; ++ii) {
      int slot = ii * 256 + tid;
      int row = slot >> 5, ch = slot & 31;
      gl2lds16(kbase + (long)row * 256 + ((ch ^ (row & 7)) << 3), &Kb[b][slot * 8]);
    }
#pragma unroll
    for (int ii = 0; ii < 8; ++ii) {
      int slot = ii * 256 + tid;
      int c = slot >> 3, ch = slot & 7;
      gl2lds16(vbase + (long)c * 1024 + ((ch ^ (c & 7)) << 3), &Vb[b][slot * 8]);
    }
  };

  stageKV(0, 0);
  __syncthreads();

  for (int jt = 0; jt < 16; ++jt) {
    const int cur = jt & 1;
    if (jt < 15) stageKV(jt + 1, cur ^ 1);

    // ---- QK^T swapped: sacc[f] = S^T[k=f*32+...][q]
    f32x16 sacc[2] = {};
#pragma unroll
    for (int kk = 0; kk < 16; ++kk) {
#pragma unroll
      for (int f = 0; f < 2; ++f) {
        int krow = f * 32 + q5;
        s8v kfr = *(const s8v*)&Kb[cur][krow * 256 + (((kk * 2 + h) ^ (q5 & 7)) << 3)];
        sacc[f] = __builtin_amdgcn_mfma_f32_32x32x16_bf16(kfr, qa[kk], sacc[f], 0, 0, 0);
      }
    }
    // ---- softmax (raw-domain max, scale folded into exp2)
    float pm = sacc[0][0];
#pragma unroll
    for (int f = 0; f < 2; ++f)
#pragma unroll
      for (int r = 0; r < 16; ++r) pm = fmaxf(pm, sacc[f][r]);
    pm = fmaxf(pm, __shfl_xor(pm, 32));
    if (!__all(pm <= m_ + 128.f)) {   // defer-max: 128 raw = 8 scaled
      float scf = exp2f((m_ - pm) * CEXP);
      l_ *= scf;
#pragma unroll
      for (int cf = 0; cf < 8; ++cf)
#pragma unroll
        for (int r = 0; r < 16; ++r) oaccT[cf][r] *= scf;
      m_ = pm;
    }
    float rs = 0.f;
#pragma unroll
    for (int f = 0; f < 2; ++f)
#pragma unroll
      for (int r = 0; r < 16; ++r) {
        float p = exp2f((sacc[f][r] - m_) * CEXP);
        sacc[f][r] = p;
        rs += p;
      }
    rs += __shfl_xor(rs, 32);
    l_ += rs;
    // ---- pack P to bf16 pairs: pk[f][g][w] = (s=2w, s=2w+1) of reg group g
    uint32_t pk[2][4][2];
#pragma unroll
    for (int f = 0; f < 2; ++f)
#pragma unroll
      for (int g = 0; g < 4; ++g) {
        pk[f][g][0] = cvtpk(sacc[f][4 * g + 0], sacc[f][4 * g + 1]);
        pk[f][g][1] = cvtpk(sacc[f][4 * g + 2], sacc[f][4 * g + 3]);
      }
    // ---- PV: O^T += mfma(V^T, P) over 4 j-slices
#pragma unroll
    for (int js = 0; js < 4; ++js) {
      const int f = js >> 1, g0 = 2 * (js & 1);
      uint32_t own0 = h ? pk[f][g0 + 1][0] : pk[f][g0][0];
      uint32_t own1 = h ? pk[f][g0 + 1][1] : pk[f][g0][1];
      uint32_t snd0 = h ? pk[f][g0][0] : pk[f][g0 + 1][0];
      uint32_t snd1 = h ? pk[f][g0][1] : pk[f][g0 + 1][1];
      uint32_t rcv0 = __shfl_xor(snd0, 32);
      uint32_t rcv1 = __shfl_xor(snd1, 32);
      u32x4 pw;
      pw[0] = h ? rcv0 : own0;
      pw[1] = h ? rcv1 : own1;
      pw[2] = h ? own0 : rcv0;
      pw[3] = h ? own1 : rcv1;
      s8v pa = __builtin_bit_cast(s8v, pw);
#pragma unroll
      for (int cf = 0; cf < 8; ++cf) {
        int c = cf * 32 + q5;
        s8v vfr = *(const s8v*)&Vb[cur][c * 64 + (((js * 2 + h) ^ (q5 & 7)) << 3)];
        oaccT[cf] = __builtin_amdgcn_mfma_f32_32x32x16_bf16(vfr, pa, oaccT[cf], 0, 0, 0);
      }
    }
    __syncthreads();
  }
  // ---- epilogue: O^T/l -> LDS transpose -> att[n][p][c]
  float inv = 1.f / l_;
  u16* tl = &Kb[0][0];  // 128 q rows x 256 c, 512B rows, chunk16 ^= (q&7)
  __syncthreads();
  const int myq = w * 32 + q5;
#pragma unroll
  for (int cf = 0; cf < 8; ++cf)
#pragma unroll
    for (int g = 0; g < 4; ++g) {
      uint32_t w0 = cvtpk(oaccT[cf][4 * g + 0] * inv, oaccT[cf][4 * g + 1] * inv);
      uint32_t w1 = cvtpk(oaccT[cf][4 * g + 2] * inv, oaccT[cf][4 * g + 3] * inv);
      int ch = (cf * 4 + g) ^ (myq & 7);
      uint2 val; val.x = w0; val.y = w1;
      *(uint2*)&tl[myq * 256 + ch * 8 + h * 4] = val;
    }
  __syncthreads();
  const int qo = tid >> 1, hr = tid & 1;
  u16* obase = attb + nbase + (long)(qt * 128 + qo) * 256;
#pragma unroll
  for (int u = 0; u < 16; ++u) {
    int c16 = hr * 16 + u;
    u32x4 v = *(const u32x4*)&tl[qo * 256 + ((c16 ^ (qo & 7)) << 3)];
    *(u32x4*)(obase + c16 * 8) = v;
  }
}

// ---------------- fused temporal q/k/v GEMM v2 -------------------------------------
__global__ __launch_bounds__(512) void qkv_t_kernel(
    const float* __restrict__ x, const u16* __restrict__ wbf,
    u16* __restrict__ qt, u16* __restrict__ kt, u16* __restrict__ vt) {
  __shared__ u16 ALDS[128 * 256];
  __shared__ u16 WLDS[2][64 * 256];
  const int bid = blockIdx.x;
  const int b = bid >> 7, st = bid & 127;
  const int s0 = st * 128;
  const int tid = threadIdx.x, w = tid >> 6, lane = tid & 63;
  const int lhi = lane >> 4, llo = lane & 15;
  const long bbase = (long)b * 4194304;

  const float* xb = x + bbase + s0;
#pragma unroll
  for (int it = 0; it < 16; ++it) {
    int idx = it * 512 + tid;
    int p = idx & 127, c4 = idx >> 7;
    us4 o;
#pragma unroll
    for (int j = 0; j < 4; ++j)
      o[j] = f2bf(xb[(long)(c4 * 4 + j) * 16384 + p]);
    int ch = c4 >> 1;
    *(us4*)&ALDS[p * 256 + ((ch ^ (p & 7)) << 3) + ((c4 & 1) << 2)] = o;
  }
  __syncthreads();
  const int arow = w * 16 + llo;
  s8v qa[8];
#pragma unroll
  for (int kk = 0; kk < 8; ++kk)
    qa[kk] = *(const s8v*)&ALDS[arow * 256 + (((kk * 4 + lhi) ^ (arow & 7)) << 3)];

  auto stageW = [&](int t, int bu) {
    const u16* wsrc = wbf + (4 + (t >> 2)) * 65536 + (long)(t & 3) * 16384;
#pragma unroll
    for (int ii = 0; ii < 4; ++ii) {
      int i0 = (w * 4 + ii) * 64;
      int g = i0 + lane;
      int row = g >> 5, ch = g & 31;
      gl2lds16(wsrc + row * 256 + ((ch ^ (row & 7)) << 3), &WLDS[bu][i0 * 8]);
    }
  };
  stageW(0, 0);
  __syncthreads();
  for (int t = 0; t < 12; ++t) {
    const int cur = t & 1;
    if (t < 11) stageW(t + 1, cur ^ 1);
    f32x4 acc[4] = {};
#pragma unroll
    for (int kk = 0; kk < 8; ++kk)
#pragma unroll
      for (int nf = 0; nf < 4; ++nf) {
        int row = nf * 16 + llo;
        s8v bb = *(const s8v*)&WLDS[cur][row * 256 + (((kk * 4 + lhi) ^ (row & 7)) << 3)];
        acc[nf] = __builtin_amdgcn_mfma_f32_16x16x32_bf16(qa[kk], bb, acc[nf], 0, 0, 0);
      }
    u16* dstb = (t < 4) ? qt : (t < 8) ? kt : vt;
    const int o0 = (t & 3) * 64;
#pragma unroll
    for (int nf = 0; nf < 4; ++nf) {
      int o = o0 + nf * 16 + llo;
#pragma unroll
      for (int r = 0; r < 4; ++r)
        dstb[bbase + (long)(s0 + w * 16 + lhi * 4 + r) * 256 + o] = f2bf(acc[nf][r]);
    }
    __syncthreads();
  }
}

// ---------------- temporal axial attention (unchanged) -----------------------------
__global__ __launch_bounds__(256) void tattn_kernel(const u16* __restrict__ qt,
                                                    const u16* __restrict__ kt,
                                                    const u16* __restrict__ vt,
                                                    u16* __restrict__ ot) {
  const int bi = blockIdx.x >> 10, hw = blockIdx.x & 1023;
  const long base = (long)bi * 4194304 + (long)hw * 256;
  __shared__ float qs[16][260], ks[16][260], vs[16][260];
  __shared__ u16 os[16][256];
  const int tid = threadIdx.x;
#pragma unroll
  for (int it = 0; it < 4; ++it) {
    int idx = it * 256 + tid;
    int t = idx >> 6, cv = idx & 63;
    long g = base + (long)t * 262144 + cv * 4;
    us4 a = *(const us4*)(qt + g);
    us4 b = *(const us4*)(kt + g);
    us4 c = *(const us4*)(vt + g);
#pragma unroll
    for (int j = 0; j < 4; ++j) {
      qs[t][cv * 4 + j] = bf2f(a[j]);
      ks[t][cv * 4 + j] = bf2f(b[j]);
      vs[t][cv * 4 + j] = bf2f(c[j]);
    }
  }
  __syncthreads();
  if (tid < 128) {
    const int h = tid >> 4, t = tid & 15;
    const int c0 = h * 32;
    float sc[16];
    float mx = -3.4e38f;
#pragma unroll
    for (int t2 = 0; t2 < 16; ++t2) {
      float d = 0.f;
#pragma unroll
      for (int dd = 0; dd < 32; ++dd) d += qs[t][c0 + dd] * ks[t2][c0 + dd];
      sc[t2] = d * 0.17677669529663687f;
      mx = fmaxf(mx, sc[t2]);
    }
    float sum = 0.f;
#pragma unroll
    for (int t2 = 0; t2 < 16; ++t2) { sc[t2] = __expf(sc[t2] - mx); sum += sc[t2]; }
    float inv = 1.f / sum;
#pragma unroll
    for (int dd = 0; dd < 32; ++dd) {
      float o = 0.f;
#pragma unroll
      for (int t2 = 0; t2 < 16; ++t2) o += sc[t2] * vs[t2][c0 + dd];
      os[t][c0 + dd] = f2bf(o * inv);
    }
  }
  __syncthreads();
#pragma unroll
  for (int it = 0; it < 4; ++it) {
    int idx = it * 256 + tid;
    int t = idx >> 6, cv = idx & 63;
    us4 o4;
#pragma unroll
    for (int j = 0; j < 4; ++j) o4[j] = os[t][cv * 4 + j];
    *(us4*)(ot + base + (long)t * 262144 + cv * 4) = o4;
  }
}

// ---------------- temporal final projection -> tmpT[b][co][s] bf16 -----------------
__global__ __launch_bounds__(512) void tfinal_kernel(
    const u16* __restrict__ ott, const u16* __restrict__ wbf,
    u16* __restrict__ tmpT) {
  __shared__ u16 ALDS[128 * 256];
  __shared__ u16 WLDS[2][64 * 256];
  const int bid = blockIdx.x;
  const int b = bid >> 7, st = bid & 127;
  const int s0 = st * 128;
  const int tid = threadIdx.x, w = tid >> 6, lane = tid & 63;
  const int lhi = lane >> 4, llo = lane & 15;
  const long bbase = (long)b * 4194304;

  const u16* otS = ott + bbase + (long)s0 * 256;
#pragma unroll
  for (int ii = 0; ii < 8; ++ii) {
    int i0 = (w * 8 + ii) * 64;
    int g = i0 + lane;
    int row = g >> 5, ch = g & 31;
    gl2lds16(otS + row * 256 + ((ch ^ (row & 7)) << 3), &ALDS[i0 * 8]);
  }
  __syncthreads();
  const int arow = w * 16 + llo;
  s8v qa[8];
#pragma unroll
  for (int kk = 0; kk < 8; ++kk)
    qa[kk] = *(const s8v*)&ALDS[arow * 256 + (((kk * 4 + lhi) ^ (arow & 7)) << 3)];

  auto stageW = [&](int t, int bu) {
    const u16* wsrc = wbf + 7 * 65536 + (long)t * 16384;
#pragma unroll
    for (int ii = 0; ii < 4; ++ii) {
      int i0 = (w * 4 + ii) * 64;
      int g = i0 + lane;
      int row = g >> 5, ch = g & 31;
      gl2lds16(wsrc + row * 256 + ((ch ^ (row & 7)) << 3), &WLDS[bu][i0 * 8]);
    }
  };
  stageW(0, 0);
  __syncthreads();
  u16* vtl = ALDS;  // safe: frags already in regs
  for (int t = 0; t < 4; ++t) {
    const int cur = t & 1;
    if (t < 3) stageW(t + 1, cur ^ 1);
    f32x4 acc[4] = {};
#pragma unroll
    for (int kk = 0; kk < 8; ++kk)
#pragma unroll
      for (int nf = 0; nf < 4; ++nf) {
        int row = nf * 16 + llo;
        s8v bb = *(const s8v*)&WLDS[cur][row * 256 + (((kk * 4 + lhi) ^ (row & 7)) << 3)];
        acc[nf] = __builtin_amdgcn_mfma_f32_16x16x32_bf16(qa[kk], bb, acc[nf], 0, 0, 0);
      }
#pragma unroll
    for (int nf = 0; nf < 4; ++nf) {
      int o = nf * 16 + llo;
#pragma unroll
      for (int r = 0; r < 4; ++r)
        vtl[o * 136 + w * 16 + lhi * 4 + r] = f2bf(acc[nf][r]);
    }
    __syncthreads();
    const int o0 = t * 64;
#pragma unroll
    for (int ii = 0; ii < 4; ++ii) {
      int i = ii * 512 + tid;
      int o = i >> 5, p4 = (i & 31) * 4;
      us4 uu;
#pragma unroll
      for (int j = 0; j < 4; ++j) uu[j] = vtl[o * 136 + p4 + j];
      *(us4*)(tmpT + bbase + (long)(o0 + o) * 16384 + s0 + p4) = uu;
    }
    __syncthreads();
  }
}

// ---------------- fused output: out = x + bo + bf + wo.att + tmpT ------------------
__global__ __launch_bounds__(256) void outproj_kernel(
    const float* __restrict__ x, const u16* __restrict__ attb,
    const u16* __restrict__ tmpT, const u16* __restrict__ wbf,
    const float* __restrict__ bo, const float* __restrict__ bf,
    float* __restrict__ out) {
  __shared__ u16 attL[64 * 256];
  const int u = blockIdx.x;
  const int wkx = (u & 7) * 256 + (u >> 3);  // XCD-chunk swizzle (2048 % 8 == 0)
  const int otile = wkx & 3, pt = (wkx >> 2) & 15, n = wkx >> 6;
  const int b = n >> 4;
  const int o0 = otile * 64, p0 = pt * 64;
  const int tid = threadIdx.x, w = tid >> 6, lane = tid & 63;
  const int lhi = lane >> 4, llo = lane & 15;
  const long nbase = (long)n * 262144;

  const u16* attS = attb + nbase + (long)p0 * 256;
#pragma unroll
  for (int ii = 0; ii < 8; ++ii) {
    int i0 = (w * 8 + ii) * 64;
    int g = i0 + lane;
    int row = g >> 5, ch = g & 31;
    gl2lds16(attS + row * 256 + ((ch ^ (row & 7)) << 3), &attL[i0 * 8]);
  }
  const u16* woR = wbf + 3 * 65536 + (long)(o0 + w * 16 + llo) * 256;
  s8v woa[8];
#pragma unroll
  for (int kk = 0; kk < 8; ++kk)
    woa[kk] = *(const s8v*)(woR + kk * 32 + lhi * 8);
  __syncthreads();
  f32x4 acc[4] = {};
#pragma unroll
  for (int kk = 0; kk < 8; ++kk)
#pragma unroll
    for (int nf = 0; nf < 4; ++nf) {
      int row = nf * 16 + llo;
      s8v b1 = *(const s8v*)&attL[row * 256 + (((kk * 4 + lhi) ^ (row & 7)) << 3)];
      acc[nf] = __builtin_amdgcn_mfma_f32_16x16x32_bf16(woa[kk], b1, acc[nf], 0, 0, 0);
    }
#pragma unroll
  for (int r = 0; r < 4; ++r) {
    int cp = o0 + w * 16 + lhi * 4 + r;          // output channel c'
    int co = ((n & 15) << 4) + (cp >> 4);        // temporal channel
    int tt = cp & 15;                            // temporal t
    float bias = bo[cp] + bf[co];
    const u16* tr = tmpT + (long)b * 4194304 + (long)co * 16384 + tt * 1024 + p0;
    const float* xr = x + nbase + (long)cp * 1024 + p0;
    float* orow = out + nbase + (long)cp * 1024 + p0;
#pragma unroll
    for (int nf = 0; nf < 4; ++nf) {
      int p = nf * 16 + llo;
      orow[p] = acc[nf][r] + bias + xr[p] + bf2f(tr[p]);
    }
  }
}

// =================================================================================
extern "C" void kernel_launch(void* const* d_in, const int* in_sizes, int n_in,
                              void* d_out, int out_size, void* d_ws, size_t ws_size,
                              hipStream_t stream) {
  const float* x     = (const float*)d_in[0];
  const float* gam   = (const float*)d_in[1];
  const float* bet   = (const float*)d_in[2];
  const float* wq_s  = (const float*)d_in[3];
  const float* bq_s  = (const float*)d_in[4];
  const float* wk_s  = (const float*)d_in[5];
  const float* bk_s  = (const float*)d_in[6];
  const float* wv_s  = (const float*)d_in[7];
  const float* bv_s  = (const float*)d_in[8];
  const float* wo_s  = (const float*)d_in[9];
  const float* bo_s  = (const float*)d_in[10];
  const float* wq_t  = (const float*)d_in[11];
  const float* wk_t  = (const float*)d_in[12];
  const float* wv_t  = (const float*)d_in[13];
  const float* wf_t  = (const float*)d_in[14];
  const float* bf_t  = (const float*)d_in[15];
  float* out = (float*)d_out;

  u16* qb   = (u16*)d_ws;           // [32][1024][256]
  u16* kb   = qb + 8388608;         // [32][1024][256]
  u16* vb   = kb + 8388608;         // [32][256][1024]
  u16* attb = vb + 8388608;         // [32][1024][256]
  u16* ottb = attb + 8388608;       // [2][16384][256]
  u16* wbf  = ottb + 8388608;       // 8 x [256][256] bf16
  float2* stats = (float2*)(wbf + 524288);
  u16* qt = qb; u16* kt = kb; u16* vt = vb;   // temporal aliases (q/k/v dead post-flash)
  u16* tmpT = qb;                              // dead post-tattn

  gn_stats_kernel<<<1024, 256, 0, stream>>>(x, stats);
  wprep_kernel<<<dim3(8, 4), 256, 0, stream>>>(wq_s, wk_s, wv_s, wo_s,
                                               wq_t, wk_t, wv_t, wf_t, wbf);
  qkv_s_kernel<<<256, 512, 0, stream>>>(x, stats, gam, bet, wbf,
                                        bq_s, bk_s, bv_s, qb, kb, vb);
  flash_kernel<<<256, 256, 0, stream>>>(qb, kb, vb, attb);
  qkv_t_kernel<<<256, 512, 0, stream>>>(x, wbf, qt, kt, vt);
  tattn_kernel<<<2048, 256, 0, stream>>>(qt, kt, vt, ottb);
  tfinal_kernel<<<256, 512, 0, stream>>>(ottb, wbf, tmpT);
  outproj_kernel<<<2048, 256, 0, stream>>>(x, attb, tmpT, wbf, bo_s, bf_t, out);
}